// Round 11
// baseline (260.009 us; speedup 1.0000x reference)
//
#include <hip/hip_runtime.h>
#include <stdint.h>
#include <stddef.h>

#define N_TOK 16384
#define DM    1024
#define DFF   4096
#define NT    4
#define TU    1024   // d_ff tile
#define TD    256    // d_model tile

typedef __attribute__((ext_vector_type(8))) short  short8;
typedef __attribute__((ext_vector_type(4))) short  short4v;
typedef __attribute__((ext_vector_type(4))) float  floatx4;

__device__ inline unsigned short f2bf(float f){
  union { float f; uint32_t u; } v; v.f = f;
  uint32_t u = v.u + 0x7FFFu + ((v.u >> 16) & 1u);   // RNE
  return (unsigned short)(u >> 16);
}

// async global->LDS, 16B per lane; lds dest is wave-uniform, lane i lands at +16*i
__device__ __forceinline__ void gll16(const void* g, void* l){
  __builtin_amdgcn_global_load_lds(
      (const __attribute__((address_space(1))) unsigned int*)g,
      (__attribute__((address_space(3))) unsigned int*)l,
      16, 0, 0);
}

// ---------------- prep: sig partial sums + w_up->bf16 ----------------------
__global__ void k_prep(const float* __restrict__ w_up,
                       float* __restrict__ partial,
                       unsigned short* __restrict__ wupb){
  const int tid = threadIdx.x;
  const int b = blockIdx.x;
  const int tile = b >> 6, chunk = b & 63;
  const int c0 = tid * 4;
  const int row0 = tile*TU + chunk*16;
  float s0=0.f, s1=0.f, s2=0.f, s3=0.f;
  const float* base = w_up + (size_t)row0 * DM + c0;
  #pragma unroll
  for (int r = 0; r < 16; ++r){
    floatx4 v = *(const floatx4*)(base + (size_t)r * DM);
    s0 += v[0]; s1 += v[1]; s2 += v[2]; s3 += v[3];
    short4v p;
    p[0]=(short)f2bf(v[0]); p[1]=(short)f2bf(v[1]);
    p[2]=(short)f2bf(v[2]); p[3]=(short)f2bf(v[3]);
    *(short4v*)(wupb + (size_t)(row0 + r) * DM + c0) = p;
  }
  float* p = partial + ((size_t)tile*DM + c0) * 64 + chunk;
  p[0] = s0; p[64] = s1; p[128] = s2; p[192] = s3;
}

// ---------------- sig finalize ----------------------------------------------
__global__ void k_sig_final(const float* __restrict__ partial,
                            float* __restrict__ sig){
  const int g = blockIdx.x * 256 + threadIdx.x;   // 0..4095 = tile*1024+col
  const float* p = partial + (size_t)g * 64;
  float s = 0.f;
  #pragma unroll
  for (int i = 0; i < 64; ++i) s += p[i];
  sig[g] = (s > 0.f) ? 1.f : ((s < 0.f) ? -1.f : 0.f);
}

// ---------------- routing (+ fused w_down->bf16 conversion) ------------------
// blocks [0,1024) = routing (16 tokens/block, 4/wave); blocks [1024,3072) =
// w_down bf16 conversion (m114 overlap; saves a launch). fp64 sum order
// UNCHANGED -> winner bit-identical.
// xbf row n lives in SECOND 2048B of out row n (ushort offset n*2048+1024).
__global__ __launch_bounds__(256) void k_route(
    const float* __restrict__ x, const float* __restrict__ sig,
    const float* __restrict__ w_down, unsigned short* __restrict__ wdownb,
    float* __restrict__ gate_out, int* __restrict__ winner,
    unsigned short* __restrict__ xbf){
  const int tid = threadIdx.x;
  if (blockIdx.x >= 1024){
    const size_t i = ((size_t)(blockIdx.x - 1024) * 256 + tid) * 8;
    floatx4 v0 = *(const floatx4*)(w_down + i);
    floatx4 v1 = *(const floatx4*)(w_down + i + 4);
    short8 p;
    p[0]=(short)f2bf(v0[0]); p[1]=(short)f2bf(v0[1]); p[2]=(short)f2bf(v0[2]); p[3]=(short)f2bf(v0[3]);
    p[4]=(short)f2bf(v1[0]); p[5]=(short)f2bf(v1[1]); p[6]=(short)f2bf(v1[2]); p[7]=(short)f2bf(v1[3]);
    *(short8*)(wdownb + i) = p;
    return;
  }
  __shared__ float ssig[NT * DM];
  for (int i = tid; i < NT*DM; i += 256) ssig[i] = sig[i];
  __syncthreads();
  const int wv = tid >> 6, lane = tid & 63;

  floatx4 sg[4][4];
  #pragma unroll
  for (int j = 0; j < 4; ++j){
    const int c = j*256 + lane*4;
    #pragma unroll
    for (int tt = 0; tt < 4; ++tt)
      sg[j][tt] = *(const floatx4*)(ssig + tt*DM + c);
  }

  #pragma unroll
  for (int t = 0; t < 4; ++t){
    const int n = blockIdx.x * 16 + wv * 4 + t;
    const float* xr = x + (size_t)n * DM;
    unsigned short* xb = xbf + (size_t)n * 2048 + 1024;
    double a0=0.0, a1=0.0, a2=0.0, a3=0.0;
    #pragma unroll
    for (int j = 0; j < 4; ++j){
      const int c = j*256 + lane*4;
      floatx4 v = *(const floatx4*)(xr + c);
      short4v p;
      p[0]=(short)f2bf(v[0]); p[1]=(short)f2bf(v[1]);
      p[2]=(short)f2bf(v[2]); p[3]=(short)f2bf(v[3]);
      *(short4v*)(xb + c) = p;
      #pragma unroll
      for (int u = 0; u < 4; ++u){
        double xv = (double)v[u];
        a0 += xv * (double)sg[j][0][u];
        a1 += xv * (double)sg[j][1][u];
        a2 += xv * (double)sg[j][2][u];
        a3 += xv * (double)sg[j][3][u];
      }
    }
    #pragma unroll
    for (int off = 32; off > 0; off >>= 1){
      a0 += __shfl_down(a0, off, 64);
      a1 += __shfl_down(a1, off, 64);
      a2 += __shfl_down(a2, off, 64);
      a3 += __shfl_down(a3, off, 64);
    }
    if (lane == 0){
      double s[4] = {a0, a1, a2, a3};
      int w = 0;
      #pragma unroll
      for (int tt = 1; tt < 4; ++tt) if (s[tt] > s[w]) w = tt;   // first-max tiebreak
      floatx4 g = { w==0 ? 1.f:0.f, w==1 ? 1.f:0.f, w==2 ? 1.f:0.f, w==3 ? 1.f:0.f };
      *(floatx4*)(gate_out + (size_t)n * 4) = g;
      winner[n] = w;
    }
  }
}

// ---------------- histogram / scan / scatter (atomic-free, deterministic) ---
__global__ void k_hist(const int* __restrict__ winner,
                       int* __restrict__ blk_cnt){   // [64][4]
  __shared__ int wcnt[4][NT];
  const int tid = threadIdx.x, wv = tid >> 6, lane = tid & 63;
  const int w = winner[blockIdx.x * 256 + tid];
  #pragma unroll
  for (int t = 0; t < NT; ++t){
    unsigned long long m = __ballot(w == t);
    if (lane == 0) wcnt[wv][t] = __popcll(m);
  }
  __syncthreads();
  if (tid < NT){
    int s = wcnt[0][tid] + wcnt[1][tid] + wcnt[2][tid] + wcnt[3][tid];
    blk_cnt[blockIdx.x * NT + tid] = s;
  }
}

__global__ void k_scan(const int* __restrict__ blk_cnt,
                       int* __restrict__ meta, int* __restrict__ blk_base){
  __shared__ int s[256];
  const int tid = threadIdx.x;
  s[tid] = blk_cnt[tid];                    // one coalesced load
  __syncthreads();
  if (tid == 0){
    int tot[NT] = {0,0,0,0};
    for (int b = 0; b < 64; ++b)
      for (int t = 0; t < NT; ++t) tot[t] += s[b*NT + t];
    int off = 0, base[NT];
    for (int t = 0; t < NT; ++t){ meta[t] = tot[t]; meta[4+t] = off; base[t] = off; off += tot[t]; }
    for (int b = 0; b < 64; ++b)
      for (int t = 0; t < NT; ++t){ int c = s[b*NT + t]; s[b*NT + t] = base[t]; base[t] += c; }
  }
  __syncthreads();
  blk_base[tid] = s[tid];                   // parallel store
}

__global__ void k_scatter(const int* __restrict__ winner,
                          const int* __restrict__ blk_base,
                          int* __restrict__ idx){
  __shared__ int wcnt[4][NT];
  const int tid = threadIdx.x, wv = tid >> 6, lane = tid & 63;
  const int n = blockIdx.x * 256 + tid;
  const int w = winner[n];
  unsigned long long mymask = 0;
  #pragma unroll
  for (int t = 0; t < NT; ++t){
    unsigned long long m = __ballot(w == t);
    if (lane == 0) wcnt[wv][t] = __popcll(m);
    if (t == w) mymask = m;
  }
  __syncthreads();
  const unsigned long long below = (lane == 0) ? 0ull : (~0ull >> (64 - lane));
  int pos = blk_base[blockIdx.x * NT + w] + __popcll(mymask & below);
  for (int v = 0; v < wv; ++v) pos += wcnt[v][w];
  idx[pos] = n;
}

// ---------------- GEMM1: hid = relu(xbf[rows] @ wupb[tile]^T + b_up) --------
// R10 version VERBATIM (51us, MfmaUtil 25, FETCH 32MB — sentinel).
__global__ __launch_bounds__(256, 2) void k_gemm1(
    const unsigned short* __restrict__ xbf,   // (ushort*)d_out; row n at n*2048+1024
    const unsigned short* __restrict__ wupb,  // [4096][1024] bf16
    const float* __restrict__ b_up, const int* __restrict__ meta,
    const int* __restrict__ idx, unsigned short* __restrict__ hid){
  // XCD swizzle: r=lin&7 -> (tile, chunk parity); q=lin>>3 -> (nb, chunk half)
  const int lin  = blockIdx.x;                 // [0,4096)
  const int r    = lin & 7, q = lin >> 3;
  const int tile = r >> 1;
  const int nb   = q & 7;
  const int chunk = ((q >> 3) << 1) | (r & 1); // [0,128)
  const int p0   = chunk * 128;

  const int cnt  = meta[tile];
  if (p0 >= cnt) return;
  const int off  = meta[4 + tile];

  __shared__ unsigned short smem[16384];  // 32768B exactly: As0|As1|Bs0|Bs1; prologue nrow + epi overlay
  unsigned short* As0 = smem;
  unsigned short* As1 = smem + 4096;
  unsigned short* Bs0 = smem + 8192;
  unsigned short* Bs1 = smem + 12288;

  const int tid = threadIdx.x;
  const int wv = tid >> 6, lane = tid & 63;
  const int wm = (wv >> 1) * 64, wn = (wv & 1) * 64;
  const int l16 = lane & 15, quad = lane >> 4;
  const int rsub = lane >> 2;          // 0..15
  const int kus  = (lane & 3) * 8;     // ushort offset within 32-elem row

  // ---- prologue: nrow via smem, consumed into registers, then smem is freed
  int* nrs = (int*)smem;               // first 512B, transient
  if (tid < 128){
    int p = p0 + tid;
    nrs[tid] = idx[off + (p < cnt ? p : cnt - 1)];
  }
  __syncthreads();
  const int ra = wv*32 + rsub;
  const unsigned short* aptr0 = xbf + (size_t)nrs[ra]      * 2048 + 1024 + kus;
  const unsigned short* aptr1 = xbf + (size_t)nrs[ra + 16] * 2048 + 1024 + kus;
  int  enr[2][4];                      // epilogue token rows (static-indexed)
  bool ev [2][4];                      // epilogue valid bits
  #pragma unroll
  for (int half = 0; half < 2; ++half){
    #pragma unroll
    for (int s = 0; s < 4; ++s){
      const int lrow = (tid + s*256) >> 4;      // 0..63
      const int m = half*64 + lrow;
      ev [half][s] = (p0 + m < cnt);
      enr[half][s] = nrs[m];
    }
  }
  __syncthreads();                     // all nrs reads done before K-loop overwrites

  const unsigned short* bptr0 = wupb + (size_t)(tile*TU + nb*128 + wv*32 + rsub) * DM + kus;
  const unsigned short* bptr1 = bptr0 + 16 * DM;

  // wave-uniform LDS dests ([row][32] layout, 64B row stride)
  unsigned short* a0d0 = As0 + (wv*32) * 32;  unsigned short* a0d1 = a0d0 + 16*32;
  unsigned short* a1d0 = As1 + (wv*32) * 32;  unsigned short* a1d1 = a1d0 + 16*32;
  unsigned short* b0d0 = Bs0 + (wv*32) * 32;  unsigned short* b0d1 = b0d0 + 16*32;
  unsigned short* b1d0 = Bs1 + (wv*32) * 32;  unsigned short* b1d1 = b1d0 + 16*32;

  floatx4 acc[4][4];
  #pragma unroll
  for (int i = 0; i < 4; ++i)
    #pragma unroll
    for (int j = 0; j < 4; ++j) acc[i][j] = (floatx4){0.f,0.f,0.f,0.f};

  for (int k0 = 0; k0 < DM; k0 += 64){
    gll16(aptr0 + k0,      a0d0);
    gll16(aptr1 + k0,      a0d1);
    gll16(aptr0 + k0 + 32, a1d0);
    gll16(aptr1 + k0 + 32, a1d1);
    gll16(bptr0 + k0,      b0d0);
    gll16(bptr1 + k0,      b0d1);
    gll16(bptr0 + k0 + 32, b1d0);
    gll16(bptr1 + k0 + 32, b1d1);
    __syncthreads();
    {
      short8 af[4], bfr[4];
      #pragma unroll
      for (int i = 0; i < 4; ++i) af[i]  = *(const short8*)(As0 + (wm + i*16 + l16)*32 + quad*8);
      #pragma unroll
      for (int j = 0; j < 4; ++j) bfr[j] = *(const short8*)(Bs0 + (wn + j*16 + l16)*32 + quad*8);
      #pragma unroll
      for (int i = 0; i < 4; ++i)
        #pragma unroll
        for (int j = 0; j < 4; ++j)
          acc[i][j] = __builtin_amdgcn_mfma_f32_16x16x32_bf16(af[i], bfr[j], acc[i][j], 0, 0, 0);
    }
    {
      short8 af[4], bfr[4];
      #pragma unroll
      for (int i = 0; i < 4; ++i) af[i]  = *(const short8*)(As1 + (wm + i*16 + l16)*32 + quad*8);
      #pragma unroll
      for (int j = 0; j < 4; ++j) bfr[j] = *(const short8*)(Bs1 + (wn + j*16 + l16)*32 + quad*8);
      #pragma unroll
      for (int i = 0; i < 4; ++i)
        #pragma unroll
        for (int j = 0; j < 4; ++j)
          acc[i][j] = __builtin_amdgcn_mfma_f32_16x16x32_bf16(af[i], bfr[j], acc[i][j], 0, 0, 0);
    }
    __syncthreads();
  }

  // epilogue: two half-passes of 64 rows through LDS (pad stride 136), wide stores
  const int gcol0 = nb*128;
  #pragma unroll
  for (int half = 0; half < 2; ++half){
    if ((wv >> 1) == half){
      #pragma unroll
      for (int i = 0; i < 4; ++i){
        #pragma unroll
        for (int j = 0; j < 4; ++j){
          const int col = wn + j*16 + l16;          // 0..127
          const float bias = b_up[tile*TU + gcol0 + col];
          #pragma unroll
          for (int r2 = 0; r2 < 4; ++r2){
            const int lrow = i*16 + quad*4 + r2;    // 0..63
            float v = acc[i][j][r2] + bias;
            smem[lrow*136 + col] = f2bf(v > 0.f ? v : 0.f);
          }
        }
      }
    }
    __syncthreads();
    // 64 rows x 16 chunks of 8 ushorts (128 cols); row ids from registers
    #pragma unroll
    for (int s = 0; s < 4; ++s){
      const int c = tid + s*256;
      const int lrow = c >> 4, k8 = (c & 15) * 8;
      if (ev[half][s]){
        short8 vv = *(const short8*)(smem + lrow*136 + k8);
        *(short8*)(hid + (size_t)enr[half][s]*2048 + gcol0 + k8) = vv;
      }
    }
    __syncthreads();
  }
}

// ---------------- GEMM2: out = hid @ wdownb[tile]^T + b_down + zero-fill ----
// BM=32 BN=256, BK=64. R11: counted-vmcnt 2-buffer pipeline (R2's proven
// machinery, applied where LDS is FREE): 2 x 36.9KB K-step buffers = 73.7KB
// -> still 2 blocks/CU (grid supplies only 2/CU: 512 active blocks).
// Iteration s: wait vmcnt(9) (own step-s loads; step-s+1's 9 stay IN FLIGHT
// across the barrier — R4's dbuf failed because __syncthreads drained
// vmcnt(0) incl. the prefetch), raw s_barrier, compute, barrier, restage
// buf s%2 with step s+2 (its readers all passed the post-compute barrier).
// sched_barrier(0) fences per rule 18. MFMA order unchanged -> bit-identical.
// Tile-into-residue XCD swizzle kept (B panel L2-resident). Zero-fill fused
// after final vmcnt(0)+barrier (all hid reads drained).
__global__ __launch_bounds__(256, 2) void k_gemm2(
    const unsigned short* __restrict__ hid,    // (ushort*)d_out; row n at n*2048
    const unsigned short* __restrict__ wdownb, // [1024][4096] bf16
    const float* __restrict__ b_down, const int* __restrict__ meta,
    const int* __restrict__ idx, float* __restrict__ out){
  const int lin  = blockIdx.x;                 // [0,2048)
  const int r    = lin & 7, q = lin >> 3;
  const int tile = r >> 1;
  const int xx   = (q << 1) | (r & 1);         // [0,512)
  const int p0   = xx * 32;

  const int cnt  = meta[tile];
  if (p0 >= cnt) return;
  const int off  = meta[4 + tile];

  // 2 K-step buffers x 18432 ushorts: per-buffer A0[0,1024)|A1[1024,2048)|
  // B0[2048,10240)|B1[10240,18432). Epilogue overlays buffer 0.
  __shared__ unsigned short smem[36864];
  float* epi = (float*)smem;              // overlay: 16 rows x 260 floats = 16640B
  __shared__ int nrow[32];

  const int tid = threadIdx.x;
  if (tid < 32){
    int p = p0 + tid;
    nrow[tid] = idx[off + (p < cnt ? p : cnt - 1)];
  }
  __syncthreads();

  const int wv = tid >> 6, lane = tid & 63;
  const int wn = wv * 64;
  const int l16 = lane & 15, quad = lane >> 4;
  const int rsub = lane >> 2;
  const int kus  = (lane & 3) * 8;

  // A: waves 0,1 stage chunk0 (rows 0-15 / 16-31); waves 2,3 stage chunk1
  const int arow = (wv & 1)*16 + rsub;
  const unsigned short* aptr = hid + (size_t)nrow[arow] * 2048 + kus;
  const int aoff = (wv >> 1) * 32;                     // k-chunk offset
  const int asdo = (wv < 2 ? 0 : 1024) + ((wv & 1)*16) * 32;
  const unsigned short* bptr = wdownb + (size_t)(tile*TD + wv*64 + rsub) * DFF + tile*TU + kus;
  const int bsd0o = 2048  + (wv*64) * 32;
  const int bsd1o = 10240 + (wv*64) * 32;

  floatx4 acc[2][4];
  #pragma unroll
  for (int i = 0; i < 2; ++i)
    #pragma unroll
    for (int j = 0; j < 4; ++j) acc[i][j] = (floatx4){0.f,0.f,0.f,0.f};

  auto stage = [&](int buf, int s){
    unsigned short* base = smem + buf*18432;
    const int k0 = s*64;
    gll16(aptr + k0 + aoff,        base + asdo);
    gll16(bptr + k0,               base + bsd0o);
    gll16(bptr + k0 + 16*DFF,      base + bsd0o + 512);
    gll16(bptr + k0 + 32*DFF,      base + bsd0o + 1024);
    gll16(bptr + k0 + 48*DFF,      base + bsd0o + 1536);
    gll16(bptr + k0 + 32,          base + bsd1o);
    gll16(bptr + k0 + 32 + 16*DFF, base + bsd1o + 512);
    gll16(bptr + k0 + 32 + 32*DFF, base + bsd1o + 1024);
    gll16(bptr + k0 + 32 + 48*DFF, base + bsd1o + 1536);
  };

  auto compute = [&](int buf){
    const unsigned short* base = smem + buf*18432;
    {
      short8 af[2], bfr[4];
      #pragma unroll
      for (int i = 0; i < 2; ++i) af[i]  = *(const short8*)(base + (i*16 + l16)*32 + quad*8);
      #pragma unroll
      for (int j = 0; j < 4; ++j) bfr[j] = *(const short8*)(base + 2048 + (wn + j*16 + l16)*32 + quad*8);
      #pragma unroll
      for (int i = 0; i < 2; ++i)
        #pragma unroll
        for (int j = 0; j < 4; ++j)
          acc[i][j] = __builtin_amdgcn_mfma_f32_16x16x32_bf16(af[i], bfr[j], acc[i][j], 0, 0, 0);
    }
    {
      short8 af[2], bfr[4];
      #pragma unroll
      for (int i = 0; i < 2; ++i) af[i]  = *(const short8*)(base + 1024 + (i*16 + l16)*32 + quad*8);
      #pragma unroll
      for (int j = 0; j < 4; ++j) bfr[j] = *(const short8*)(base + 10240 + (wn + j*16 + l16)*32 + quad*8);
      #pragma unroll
      for (int i = 0; i < 2; ++i)
        #pragma unroll
        for (int j = 0; j < 4; ++j)
          acc[i][j] = __builtin_amdgcn_mfma_f32_16x16x32_bf16(af[i], bfr[j], acc[i][j], 0, 0, 0);
    }
  };

  // prologue: steps 0 and 1 in flight (18 outstanding loads/wave)
  stage(0, 0);
  stage(1, 1);

  for (int s = 0; s < 16; ++s){
    // wait for step-s loads only; step-(s+1)'s 9 stay in flight across barrier
    if (s == 15) asm volatile("s_waitcnt vmcnt(0)" ::: "memory");
    else         asm volatile("s_waitcnt vmcnt(9)" ::: "memory");
    __builtin_amdgcn_s_barrier();            // all waves' buf-s loads landed
    __builtin_amdgcn_sched_barrier(0);       // rule 18: no ds_read hoist above
    compute(s & 1);
    __builtin_amdgcn_sched_barrier(0);
    asm volatile("" ::: "memory");
    __builtin_amdgcn_s_barrier();            // all reads of buf s%2 done
    if (s < 14) stage(s & 1, s + 2);         // safe: readers passed barrier
  }

  // zero-fill non-winner 256-col blocks of OWN tokens (hid reads all drained)
  const floatx4 z4 = {0.f, 0.f, 0.f, 0.f};
  #pragma unroll
  for (int cb = 0; cb < 4; ++cb){
    if (cb == tile) continue;
    for (int c = tid; c < 32*64; c += 256){
      const int rowl = c >> 6, c4 = (c & 63) * 4;
      if (p0 + rowl < cnt)
        *(floatx4*)(out + (size_t)nrow[rowl]*DM + cb*256 + c4) = z4;
    }
  }

  // epilogue: two half-passes of 16 rows via LDS fp32 (pad stride 260), float4 stores
  #pragma unroll
  for (int half = 0; half < 2; ++half){
    #pragma unroll
    for (int j = 0; j < 4; ++j){
      const int col = wn + j*16 + l16;              // 0..255
      const float bias = b_down[tile*TD + col];
      #pragma unroll
      for (int r2 = 0; r2 < 4; ++r2){
        const int lrow = quad*4 + r2;               // 0..15
        epi[lrow*260 + col] = acc[half][j][r2] + bias;
      }
    }
    __syncthreads();
    #pragma unroll
    for (int c = tid; c < 1024; c += 256){          // 16 rows x 64 float4 chunks
      const int lrow = c >> 6, c4 = (c & 63) * 4;
      const int m = half*16 + lrow;
      if (p0 + m < cnt){
        floatx4 v = *(const floatx4*)(epi + lrow*260 + c4);
        *(floatx4*)(out + (size_t)nrow[m]*DM + tile*TD + c4) = v;
      }
    }
    __syncthreads();
  }
}

extern "C" void kernel_launch(void* const* d_in, const int* in_sizes, int n_in,
                              void* d_out, int out_size, void* d_ws, size_t ws_size,
                              hipStream_t stream){
  const float* x      = (const float*)d_in[0];
  const float* w_up   = (const float*)d_in[1];
  const float* b_up   = (const float*)d_in[2];
  const float* w_down = (const float*)d_in[3];
  const float* b_down = (const float*)d_in[4];

  // ws layout (~17.3 MB; proven layout)
  unsigned short* wupb   = (unsigned short*)d_ws;            // 4096*1024 bf16 = 8 MB
  unsigned short* wdownb = wupb + (size_t)DFF * DM;          // 1024*4096 bf16 = 8 MB
  float* partial = (float*)(wdownb + (size_t)DM * DFF);      // 262144 floats = 1 MB
  float* sig     = partial + 262144;                         // 4096 floats
  int*   ints    = (int*)(sig + 4096);
  int*   winner   = ints;                                    // 16384
  int*   idx      = ints + 16384;                            // 16384
  int*   meta     = ints + 32768;                            // [0..3]=counts [4..7]=offsets
  int*   blk_cnt  = ints + 32776;                            // [64][4]
  int*   blk_base = ints + 33032;                            // [64][4]

  float*          out  = (float*)d_out;
  float*          gate = out + (size_t)N_TOK * DM;
  unsigned short* ob16 = (unsigned short*)d_out;  // row n: hid at n*2048, xbf at n*2048+1024

  k_prep      <<<dim3(256),  256, 0, stream>>>(w_up, partial, wupb);
  k_sig_final <<<dim3(16),   256, 0, stream>>>(partial, sig);
  k_route     <<<dim3(3072), 256, 0, stream>>>(x, sig, w_down, wdownb, gate, winner, ob16);
  k_hist      <<<dim3(64),   256, 0, stream>>>(winner, blk_cnt);
  k_scan      <<<dim3(1),    256, 0, stream>>>(blk_cnt, meta, blk_base);
  k_scatter   <<<dim3(64),   256, 0, stream>>>(winner, blk_base, idx);
  k_gemm1     <<<dim3(4096), 256, 0, stream>>>(ob16, wupb, b_up, meta, idx, ob16);
  k_gemm2     <<<dim3(2048), 256, 0, stream>>>(ob16, wdownb, b_down, meta, idx, out);
}

// Round 12
// 255.755 us; speedup vs baseline: 1.0166x; 1.0166x over previous
//
#include <hip/hip_runtime.h>
#include <stdint.h>
#include <stddef.h>

#define N_TOK 16384
#define DM    1024
#define DFF   4096
#define NT    4
#define TU    1024   // d_ff tile
#define TD    256    // d_model tile

typedef __attribute__((ext_vector_type(8))) short  short8;
typedef __attribute__((ext_vector_type(4))) short  short4v;
typedef __attribute__((ext_vector_type(4))) float  floatx4;

__device__ inline unsigned short f2bf(float f){
  union { float f; uint32_t u; } v; v.f = f;
  uint32_t u = v.u + 0x7FFFu + ((v.u >> 16) & 1u);   // RNE
  return (unsigned short)(u >> 16);
}

// async global->LDS, 16B per lane; lds dest is wave-uniform, lane i lands at +16*i
__device__ __forceinline__ void gll16(const void* g, void* l){
  __builtin_amdgcn_global_load_lds(
      (const __attribute__((address_space(1))) unsigned int*)g,
      (__attribute__((address_space(3))) unsigned int*)l,
      16, 0, 0);
}

// ---------------- prep: sig partial sums + w_up->bf16 ----------------------
__global__ void k_prep(const float* __restrict__ w_up,
                       float* __restrict__ partial,
                       unsigned short* __restrict__ wupb){
  const int tid = threadIdx.x;
  const int b = blockIdx.x;
  const int tile = b >> 6, chunk = b & 63;
  const int c0 = tid * 4;
  const int row0 = tile*TU + chunk*16;
  float s0=0.f, s1=0.f, s2=0.f, s3=0.f;
  const float* base = w_up + (size_t)row0 * DM + c0;
  #pragma unroll
  for (int r = 0; r < 16; ++r){
    floatx4 v = *(const floatx4*)(base + (size_t)r * DM);
    s0 += v[0]; s1 += v[1]; s2 += v[2]; s3 += v[3];
    short4v p;
    p[0]=(short)f2bf(v[0]); p[1]=(short)f2bf(v[1]);
    p[2]=(short)f2bf(v[2]); p[3]=(short)f2bf(v[3]);
    *(short4v*)(wupb + (size_t)(row0 + r) * DM + c0) = p;
  }
  float* p = partial + ((size_t)tile*DM + c0) * 64 + chunk;
  p[0] = s0; p[64] = s1; p[128] = s2; p[192] = s3;
}

// ---------------- sig finalize (+ zero blk_cnt for route's fused hist) ------
__global__ void k_sig_final(const float* __restrict__ partial,
                            float* __restrict__ sig,
                            int* __restrict__ blk_cnt){
  if (blockIdx.x == 0) blk_cnt[threadIdx.x] = 0;   // 256 ints, re-zeroed each replay
  const int g = blockIdx.x * 256 + threadIdx.x;    // 0..4095 = tile*1024+col
  const float* p = partial + (size_t)g * 64;
  float s = 0.f;
  #pragma unroll
  for (int i = 0; i < 64; ++i) s += p[i];
  sig[g] = (s > 0.f) ? 1.f : ((s < 0.f) ? -1.f : 0.f);
}

// ---------------- routing (+ fused w_down conv + fused histogram) -----------
// blocks [0,1024) = routing (16 tokens/block, 4/wave); blocks [1024,3072) =
// w_down bf16 conversion (m114 overlap). fp64 sum order UNCHANGED -> winner
// bit-identical. R12: per-block winner counts atomicAdd'ed into
// blk_cnt[blockIdx>>4] (integer add commutative -> deterministic counts;
// scan/scatter inputs bit-identical; k_hist launch deleted).
// xbf row n lives in SECOND 2048B of out row n (ushort offset n*2048+1024).
__global__ __launch_bounds__(256) void k_route(
    const float* __restrict__ x, const float* __restrict__ sig,
    const float* __restrict__ w_down, unsigned short* __restrict__ wdownb,
    float* __restrict__ gate_out, int* __restrict__ winner,
    int* __restrict__ blk_cnt, unsigned short* __restrict__ xbf){
  const int tid = threadIdx.x;
  if (blockIdx.x >= 1024){
    const size_t i = ((size_t)(blockIdx.x - 1024) * 256 + tid) * 8;
    floatx4 v0 = *(const floatx4*)(w_down + i);
    floatx4 v1 = *(const floatx4*)(w_down + i + 4);
    short8 p;
    p[0]=(short)f2bf(v0[0]); p[1]=(short)f2bf(v0[1]); p[2]=(short)f2bf(v0[2]); p[3]=(short)f2bf(v0[3]);
    p[4]=(short)f2bf(v1[0]); p[5]=(short)f2bf(v1[1]); p[6]=(short)f2bf(v1[2]); p[7]=(short)f2bf(v1[3]);
    *(short8*)(wdownb + i) = p;
    return;
  }
  __shared__ float ssig[NT * DM];
  __shared__ int swin[16];
  for (int i = tid; i < NT*DM; i += 256) ssig[i] = sig[i];
  __syncthreads();
  const int wv = tid >> 6, lane = tid & 63;

  floatx4 sg[4][4];
  #pragma unroll
  for (int j = 0; j < 4; ++j){
    const int c = j*256 + lane*4;
    #pragma unroll
    for (int tt = 0; tt < 4; ++tt)
      sg[j][tt] = *(const floatx4*)(ssig + tt*DM + c);
  }

  #pragma unroll
  for (int t = 0; t < 4; ++t){
    const int n = blockIdx.x * 16 + wv * 4 + t;
    const float* xr = x + (size_t)n * DM;
    unsigned short* xb = xbf + (size_t)n * 2048 + 1024;
    double a0=0.0, a1=0.0, a2=0.0, a3=0.0;
    #pragma unroll
    for (int j = 0; j < 4; ++j){
      const int c = j*256 + lane*4;
      floatx4 v = *(const floatx4*)(xr + c);
      short4v p;
      p[0]=(short)f2bf(v[0]); p[1]=(short)f2bf(v[1]);
      p[2]=(short)f2bf(v[2]); p[3]=(short)f2bf(v[3]);
      *(short4v*)(xb + c) = p;
      #pragma unroll
      for (int u = 0; u < 4; ++u){
        double xv = (double)v[u];
        a0 += xv * (double)sg[j][0][u];
        a1 += xv * (double)sg[j][1][u];
        a2 += xv * (double)sg[j][2][u];
        a3 += xv * (double)sg[j][3][u];
      }
    }
    #pragma unroll
    for (int off = 32; off > 0; off >>= 1){
      a0 += __shfl_down(a0, off, 64);
      a1 += __shfl_down(a1, off, 64);
      a2 += __shfl_down(a2, off, 64);
      a3 += __shfl_down(a3, off, 64);
    }
    if (lane == 0){
      double s[4] = {a0, a1, a2, a3};
      int w = 0;
      #pragma unroll
      for (int tt = 1; tt < 4; ++tt) if (s[tt] > s[w]) w = tt;   // first-max tiebreak
      floatx4 g = { w==0 ? 1.f:0.f, w==1 ? 1.f:0.f, w==2 ? 1.f:0.f, w==3 ? 1.f:0.f };
      *(floatx4*)(gate_out + (size_t)n * 4) = g;
      winner[n] = w;
      swin[wv*4 + t] = w;
    }
  }
  __syncthreads();
  // fused histogram: this block's 16 winners -> segment blockIdx>>4 counts
  if (tid < NT){
    int c = 0;
    #pragma unroll
    for (int i = 0; i < 16; ++i) c += (swin[i] == tid) ? 1 : 0;
    if (c) atomicAdd(&blk_cnt[(blockIdx.x >> 4) * NT + tid], c);
  }
}

// ---------------- scan / scatter (atomic-free, deterministic) ----------------
__global__ void k_scan(const int* __restrict__ blk_cnt,
                       int* __restrict__ meta, int* __restrict__ blk_base){
  __shared__ int s[256];
  const int tid = threadIdx.x;
  s[tid] = blk_cnt[tid];                    // one coalesced load
  __syncthreads();
  if (tid == 0){
    int tot[NT] = {0,0,0,0};
    for (int b = 0; b < 64; ++b)
      for (int t = 0; t < NT; ++t) tot[t] += s[b*NT + t];
    int off = 0, base[NT];
    for (int t = 0; t < NT; ++t){ meta[t] = tot[t]; meta[4+t] = off; base[t] = off; off += tot[t]; }
    for (int b = 0; b < 64; ++b)
      for (int t = 0; t < NT; ++t){ int c = s[b*NT + t]; s[b*NT + t] = base[t]; base[t] += c; }
  }
  __syncthreads();
  blk_base[tid] = s[tid];                   // parallel store
}

__global__ void k_scatter(const int* __restrict__ winner,
                          const int* __restrict__ blk_base,
                          int* __restrict__ idx){
  __shared__ int wcnt[4][NT];
  const int tid = threadIdx.x, wv = tid >> 6, lane = tid & 63;
  const int n = blockIdx.x * 256 + tid;
  const int w = winner[n];
  unsigned long long mymask = 0;
  #pragma unroll
  for (int t = 0; t < NT; ++t){
    unsigned long long m = __ballot(w == t);
    if (lane == 0) wcnt[wv][t] = __popcll(m);
    if (t == w) mymask = m;
  }
  __syncthreads();
  const unsigned long long below = (lane == 0) ? 0ull : (~0ull >> (64 - lane));
  int pos = blk_base[blockIdx.x * NT + w] + __popcll(mymask & below);
  for (int v = 0; v < wv; ++v) pos += wcnt[v][w];
  idx[pos] = n;
}

// ---------------- GEMM1: hid = relu(xbf[rows] @ wupb[tile]^T + b_up) --------
// R10 version VERBATIM (51us, MfmaUtil 26, FETCH 32MB — sentinel).
__global__ __launch_bounds__(256, 2) void k_gemm1(
    const unsigned short* __restrict__ xbf,   // (ushort*)d_out; row n at n*2048+1024
    const unsigned short* __restrict__ wupb,  // [4096][1024] bf16
    const float* __restrict__ b_up, const int* __restrict__ meta,
    const int* __restrict__ idx, unsigned short* __restrict__ hid){
  // XCD swizzle: r=lin&7 -> (tile, chunk parity); q=lin>>3 -> (nb, chunk half)
  const int lin  = blockIdx.x;                 // [0,4096)
  const int r    = lin & 7, q = lin >> 3;
  const int tile = r >> 1;
  const int nb   = q & 7;
  const int chunk = ((q >> 3) << 1) | (r & 1); // [0,128)
  const int p0   = chunk * 128;

  const int cnt  = meta[tile];
  if (p0 >= cnt) return;
  const int off  = meta[4 + tile];

  __shared__ unsigned short smem[16384];  // 32768B exactly: As0|As1|Bs0|Bs1; prologue nrow + epi overlay
  unsigned short* As0 = smem;
  unsigned short* As1 = smem + 4096;
  unsigned short* Bs0 = smem + 8192;
  unsigned short* Bs1 = smem + 12288;

  const int tid = threadIdx.x;
  const int wv = tid >> 6, lane = tid & 63;
  const int wm = (wv >> 1) * 64, wn = (wv & 1) * 64;
  const int l16 = lane & 15, quad = lane >> 4;
  const int rsub = lane >> 2;          // 0..15
  const int kus  = (lane & 3) * 8;     // ushort offset within 32-elem row

  // ---- prologue: nrow via smem, consumed into registers, then smem is freed
  int* nrs = (int*)smem;               // first 512B, transient
  if (tid < 128){
    int p = p0 + tid;
    nrs[tid] = idx[off + (p < cnt ? p : cnt - 1)];
  }
  __syncthreads();
  const int ra = wv*32 + rsub;
  const unsigned short* aptr0 = xbf + (size_t)nrs[ra]      * 2048 + 1024 + kus;
  const unsigned short* aptr1 = xbf + (size_t)nrs[ra + 16] * 2048 + 1024 + kus;
  int  enr[2][4];                      // epilogue token rows (static-indexed)
  bool ev [2][4];                      // epilogue valid bits
  #pragma unroll
  for (int half = 0; half < 2; ++half){
    #pragma unroll
    for (int s = 0; s < 4; ++s){
      const int lrow = (tid + s*256) >> 4;      // 0..63
      const int m = half*64 + lrow;
      ev [half][s] = (p0 + m < cnt);
      enr[half][s] = nrs[m];
    }
  }
  __syncthreads();                     // all nrs reads done before K-loop overwrites

  const unsigned short* bptr0 = wupb + (size_t)(tile*TU + nb*128 + wv*32 + rsub) * DM + kus;
  const unsigned short* bptr1 = bptr0 + 16 * DM;

  // wave-uniform LDS dests ([row][32] layout, 64B row stride)
  unsigned short* a0d0 = As0 + (wv*32) * 32;  unsigned short* a0d1 = a0d0 + 16*32;
  unsigned short* a1d0 = As1 + (wv*32) * 32;  unsigned short* a1d1 = a1d0 + 16*32;
  unsigned short* b0d0 = Bs0 + (wv*32) * 32;  unsigned short* b0d1 = b0d0 + 16*32;
  unsigned short* b1d0 = Bs1 + (wv*32) * 32;  unsigned short* b1d1 = b1d0 + 16*32;

  floatx4 acc[4][4];
  #pragma unroll
  for (int i = 0; i < 4; ++i)
    #pragma unroll
    for (int j = 0; j < 4; ++j) acc[i][j] = (floatx4){0.f,0.f,0.f,0.f};

  for (int k0 = 0; k0 < DM; k0 += 64){
    gll16(aptr0 + k0,      a0d0);
    gll16(aptr1 + k0,      a0d1);
    gll16(aptr0 + k0 + 32, a1d0);
    gll16(aptr1 + k0 + 32, a1d1);
    gll16(bptr0 + k0,      b0d0);
    gll16(bptr1 + k0,      b0d1);
    gll16(bptr0 + k0 + 32, b1d0);
    gll16(bptr1 + k0 + 32, b1d1);
    __syncthreads();
    {
      short8 af[4], bfr[4];
      #pragma unroll
      for (int i = 0; i < 4; ++i) af[i]  = *(const short8*)(As0 + (wm + i*16 + l16)*32 + quad*8);
      #pragma unroll
      for (int j = 0; j < 4; ++j) bfr[j] = *(const short8*)(Bs0 + (wn + j*16 + l16)*32 + quad*8);
      #pragma unroll
      for (int i = 0; i < 4; ++i)
        #pragma unroll
        for (int j = 0; j < 4; ++j)
          acc[i][j] = __builtin_amdgcn_mfma_f32_16x16x32_bf16(af[i], bfr[j], acc[i][j], 0, 0, 0);
    }
    {
      short8 af[4], bfr[4];
      #pragma unroll
      for (int i = 0; i < 4; ++i) af[i]  = *(const short8*)(As1 + (wm + i*16 + l16)*32 + quad*8);
      #pragma unroll
      for (int j = 0; j < 4; ++j) bfr[j] = *(const short8*)(Bs1 + (wn + j*16 + l16)*32 + quad*8);
      #pragma unroll
      for (int i = 0; i < 4; ++i)
        #pragma unroll
        for (int j = 0; j < 4; ++j)
          acc[i][j] = __builtin_amdgcn_mfma_f32_16x16x32_bf16(af[i], bfr[j], acc[i][j], 0, 0, 0);
    }
    __syncthreads();
  }

  // epilogue: two half-passes of 64 rows through LDS (pad stride 136), wide stores
  const int gcol0 = nb*128;
  #pragma unroll
  for (int half = 0; half < 2; ++half){
    if ((wv >> 1) == half){
      #pragma unroll
      for (int i = 0; i < 4; ++i){
        #pragma unroll
        for (int j = 0; j < 4; ++j){
          const int col = wn + j*16 + l16;          // 0..127
          const float bias = b_up[tile*TU + gcol0 + col];
          #pragma unroll
          for (int r2 = 0; r2 < 4; ++r2){
            const int lrow = i*16 + quad*4 + r2;    // 0..63
            float v = acc[i][j][r2] + bias;
            smem[lrow*136 + col] = f2bf(v > 0.f ? v : 0.f);
          }
        }
      }
    }
    __syncthreads();
    // 64 rows x 16 chunks of 8 ushorts (128 cols); row ids from registers
    #pragma unroll
    for (int s = 0; s < 4; ++s){
      const int c = tid + s*256;
      const int lrow = c >> 4, k8 = (c & 15) * 8;
      if (ev[half][s]){
        short8 vv = *(const short8*)(smem + lrow*136 + k8);
        *(short8*)(hid + (size_t)enr[half][s]*2048 + gcol0 + k8) = vv;
      }
    }
    __syncthreads();
  }
}

// ---------------- GEMM2: out = hid @ wdownb[tile]^T + b_down + zero-fill ----
// BM=32 BN=256, BK=64 paired buffers — R10 version VERBATIM (R11's counted-
// vmcnt pipeline +3us, R4's simple dbuf also ~+3: at 2 blk/CU x 4 waves with
// L2-resident B, wave TLP already covers load latency; plain 2-barrier loop
// is locally optimal). Tile-into-residue XCD swizzle kept. Zero-fill fused
// after K-loop's final barrier.
__global__ __launch_bounds__(256, 2) void k_gemm2(
    const unsigned short* __restrict__ hid,    // (ushort*)d_out; row n at n*2048
    const unsigned short* __restrict__ wdownb, // [1024][4096] bf16
    const float* __restrict__ b_down, const int* __restrict__ meta,
    const int* __restrict__ idx, float* __restrict__ out){
  const int lin  = blockIdx.x;                 // [0,2048)
  const int r    = lin & 7, q = lin >> 3;
  const int tile = r >> 1;
  const int xx   = (q << 1) | (r & 1);         // [0,512)
  const int p0   = xx * 32;

  const int cnt  = meta[tile];
  if (p0 >= cnt) return;
  const int off  = meta[4 + tile];

  __shared__ unsigned short smem[18432];  // As0|As1 (1024 each) | Bs0|Bs1 (8192 each)
  unsigned short* As0 = smem;
  unsigned short* As1 = smem + 1024;
  unsigned short* Bs0 = smem + 2048;
  unsigned short* Bs1 = smem + 10240;
  float* epi = (float*)smem;              // overlay: 16 rows x 260 floats = 16640B
  __shared__ int nrow[32];

  const int tid = threadIdx.x;
  if (tid < 32){
    int p = p0 + tid;
    nrow[tid] = idx[off + (p < cnt ? p : cnt - 1)];
  }
  __syncthreads();

  const int wv = tid >> 6, lane = tid & 63;
  const int wn = wv * 64;
  const int l16 = lane & 15, quad = lane >> 4;

  const int rsub = lane >> 2;
  const int kus  = (lane & 3) * 8;

  const int arow = (wv & 1)*16 + rsub;
  const unsigned short* aptr = hid + (size_t)nrow[arow] * 2048 + kus;
  const int aoff = (wv >> 1) * 32;                     // k-chunk offset
  unsigned short* asd = (wv < 2 ? As0 : As1) + ((wv & 1)*16) * 32;
  const unsigned short* bptr = wdownb + (size_t)(tile*TD + wv*64 + rsub) * DFF + tile*TU + kus;
  unsigned short* bsd0 = Bs0 + (wv*64) * 32;
  unsigned short* bsd1 = Bs1 + (wv*64) * 32;

  floatx4 acc[2][4];
  #pragma unroll
  for (int i = 0; i < 2; ++i)
    #pragma unroll
    for (int j = 0; j < 4; ++j) acc[i][j] = (floatx4){0.f,0.f,0.f,0.f};

  for (int k0 = 0; k0 < TU; k0 += 64){
    gll16(aptr + k0 + aoff, asd);
    gll16(bptr + k0,               bsd0);
    gll16(bptr + k0 + 16*DFF,      bsd0 + 16*32);
    gll16(bptr + k0 + 32*DFF,      bsd0 + 32*32);
    gll16(bptr + k0 + 48*DFF,      bsd0 + 48*32);
    gll16(bptr + k0 + 32,          bsd1);
    gll16(bptr + k0 + 32 + 16*DFF, bsd1 + 16*32);
    gll16(bptr + k0 + 32 + 32*DFF, bsd1 + 32*32);
    gll16(bptr + k0 + 32 + 48*DFF, bsd1 + 48*32);
    __syncthreads();
    {
      short8 af[2], bfr[4];
      #pragma unroll
      for (int i = 0; i < 2; ++i) af[i]  = *(const short8*)(As0 + (i*16 + l16)*32 + quad*8);
      #pragma unroll
      for (int j = 0; j < 4; ++j) bfr[j] = *(const short8*)(Bs0 + (wn + j*16 + l16)*32 + quad*8);
      #pragma unroll
      for (int i = 0; i < 2; ++i)
        #pragma unroll
        for (int j = 0; j < 4; ++j)
          acc[i][j] = __builtin_amdgcn_mfma_f32_16x16x32_bf16(af[i], bfr[j], acc[i][j], 0, 0, 0);
    }
    {
      short8 af[2], bfr[4];
      #pragma unroll
      for (int i = 0; i < 2; ++i) af[i]  = *(const short8*)(As1 + (i*16 + l16)*32 + quad*8);
      #pragma unroll
      for (int j = 0; j < 4; ++j) bfr[j] = *(const short8*)(Bs1 + (wn + j*16 + l16)*32 + quad*8);
      #pragma unroll
      for (int i = 0; i < 2; ++i)
        #pragma unroll
        for (int j = 0; j < 4; ++j)
          acc[i][j] = __builtin_amdgcn_mfma_f32_16x16x32_bf16(af[i], bfr[j], acc[i][j], 0, 0, 0);
    }
    __syncthreads();
  }

  // zero-fill non-winner 256-col blocks of OWN tokens (hid reads all drained)
  const floatx4 z4 = {0.f, 0.f, 0.f, 0.f};
  #pragma unroll
  for (int cb = 0; cb < 4; ++cb){
    if (cb == tile) continue;
    for (int c = tid; c < 32*64; c += 256){
      const int rowl = c >> 6, c4 = (c & 63) * 4;
      if (p0 + rowl < cnt)
        *(floatx4*)(out + (size_t)nrow[rowl]*DM + cb*256 + c4) = z4;
    }
  }

  // epilogue: two half-passes of 16 rows via LDS fp32 (pad stride 260), float4 stores
  #pragma unroll
  for (int half = 0; half < 2; ++half){
    #pragma unroll
    for (int j = 0; j < 4; ++j){
      const int col = wn + j*16 + l16;              // 0..255
      const float bias = b_down[tile*TD + col];
      #pragma unroll
      for (int r2 = 0; r2 < 4; ++r2){
        const int lrow = quad*4 + r2;               // 0..15
        epi[lrow*260 + col] = acc[half][j][r2] + bias;
      }
    }
    __syncthreads();
    #pragma unroll
    for (int c = tid; c < 1024; c += 256){          // 16 rows x 64 float4 chunks
      const int lrow = c >> 6, c4 = (c & 63) * 4;
      const int m = half*16 + lrow;
      if (p0 + m < cnt){
        floatx4 v = *(const floatx4*)(epi + lrow*260 + c4);
        *(floatx4*)(out + (size_t)nrow[m]*DM + tile*TD + c4) = v;
      }
    }
    __syncthreads();
  }
}

extern "C" void kernel_launch(void* const* d_in, const int* in_sizes, int n_in,
                              void* d_out, int out_size, void* d_ws, size_t ws_size,
                              hipStream_t stream){
  const float* x      = (const float*)d_in[0];
  const float* w_up   = (const float*)d_in[1];
  const float* b_up   = (const float*)d_in[2];
  const float* w_down = (const float*)d_in[3];
  const float* b_down = (const float*)d_in[4];

  // ws layout (~17.3 MB; proven layout)
  unsigned short* wupb   = (unsigned short*)d_ws;            // 4096*1024 bf16 = 8 MB
  unsigned short* wdownb = wupb + (size_t)DFF * DM;          // 1024*4096 bf16 = 8 MB
  float* partial = (float*)(wdownb + (size_t)DM * DFF);      // 262144 floats = 1 MB
  float* sig     = partial + 262144;                         // 4096 floats
  int*   ints    = (int*)(sig + 4096);
  int*   winner   = ints;                                    // 16384
  int*   idx      = ints + 16384;                            // 16384
  int*   meta     = ints + 32768;                            // [0..3]=counts [4..7]=offsets
  int*   blk_cnt  = ints + 32776;                            // [64][4]
  int*   blk_base = ints + 33032;                            // [64][4]

  float*          out  = (float*)d_out;
  float*          gate = out + (size_t)N_TOK * DM;
  unsigned short* ob16 = (unsigned short*)d_out;  // row n: hid at n*2048, xbf at n*2048+1024

  k_prep      <<<dim3(256),  256, 0, stream>>>(w_up, partial, wupb);
  k_sig_final <<<dim3(16),   256, 0, stream>>>(partial, sig, blk_cnt);
  k_route     <<<dim3(3072), 256, 0, stream>>>(x, sig, w_down, wdownb, gate, winner, blk_cnt, ob16);
  k_scan      <<<dim3(1),    256, 0, stream>>>(blk_cnt, meta, blk_base);
  k_scatter   <<<dim3(64),   256, 0, stream>>>(winner, blk_base, idx);
  k_gemm1     <<<dim3(4096), 256, 0, stream>>>(ob16, wupb, b_up, meta, idx, ob16);
  k_gemm2     <<<dim3(2048), 256, 0, stream>>>(ob16, wdownb, b_down, meta, idx, out);
}

// Round 13
// 253.866 us; speedup vs baseline: 1.0242x; 1.0074x over previous
//
#include <hip/hip_runtime.h>
#include <stdint.h>
#include <stddef.h>

#define N_TOK 16384
#define DM    1024
#define DFF   4096
#define NT    4
#define TU    1024   // d_ff tile
#define TD    256    // d_model tile

typedef __attribute__((ext_vector_type(8))) short  short8;
typedef __attribute__((ext_vector_type(4))) short  short4v;
typedef __attribute__((ext_vector_type(4))) float  floatx4;

__device__ inline unsigned short f2bf(float f){
  union { float f; uint32_t u; } v; v.f = f;
  uint32_t u = v.u + 0x7FFFu + ((v.u >> 16) & 1u);   // RNE
  return (unsigned short)(u >> 16);
}

// async global->LDS, 16B per lane; lds dest is wave-uniform, lane i lands at +16*i
__device__ __forceinline__ void gll16(const void* g, void* l){
  __builtin_amdgcn_global_load_lds(
      (const __attribute__((address_space(1))) unsigned int*)g,
      (__attribute__((address_space(3))) unsigned int*)l,
      16, 0, 0);
}

// ---------------- prep: sig partial sums + w_up->bf16 ----------------------
__global__ void k_prep(const float* __restrict__ w_up,
                       float* __restrict__ partial,
                       unsigned short* __restrict__ wupb){
  const int tid = threadIdx.x;
  const int b = blockIdx.x;
  const int tile = b >> 6, chunk = b & 63;
  const int c0 = tid * 4;
  const int row0 = tile*TU + chunk*16;
  float s0=0.f, s1=0.f, s2=0.f, s3=0.f;
  const float* base = w_up + (size_t)row0 * DM + c0;
  #pragma unroll
  for (int r = 0; r < 16; ++r){
    floatx4 v = *(const floatx4*)(base + (size_t)r * DM);
    s0 += v[0]; s1 += v[1]; s2 += v[2]; s3 += v[3];
    short4v p;
    p[0]=(short)f2bf(v[0]); p[1]=(short)f2bf(v[1]);
    p[2]=(short)f2bf(v[2]); p[3]=(short)f2bf(v[3]);
    *(short4v*)(wupb + (size_t)(row0 + r) * DM + c0) = p;
  }
  float* p = partial + ((size_t)tile*DM + c0) * 64 + chunk;
  p[0] = s0; p[64] = s1; p[128] = s2; p[192] = s3;
}

// ---------------- sig finalize (+ zero blk_cnt for route's fused hist) ------
__global__ void k_sig_final(const float* __restrict__ partial,
                            float* __restrict__ sig,
                            int* __restrict__ blk_cnt){
  if (blockIdx.x == 0) blk_cnt[threadIdx.x] = 0;   // 256 ints, re-zeroed each replay
  const int g = blockIdx.x * 256 + threadIdx.x;    // 0..4095 = tile*1024+col
  const float* p = partial + (size_t)g * 64;
  float s = 0.f;
  #pragma unroll
  for (int i = 0; i < 64; ++i) s += p[i];
  sig[g] = (s > 0.f) ? 1.f : ((s < 0.f) ? -1.f : 0.f);
}

// ---------------- routing (+ fused w_down conv + fused histogram) -----------
// blocks [0,1024) = routing (16 tokens/block, 4/wave); blocks [1024,3072) =
// w_down bf16 conversion (m114 overlap). fp64 sum order UNCHANGED -> winner
// bit-identical. Per-block winner counts atomicAdd'ed into blk_cnt
// (integer add commutative -> deterministic; scan/scatter inputs identical).
// xbf row n lives in SECOND 2048B of out row n (ushort offset n*2048+1024).
__global__ __launch_bounds__(256) void k_route(
    const float* __restrict__ x, const float* __restrict__ sig,
    const float* __restrict__ w_down, unsigned short* __restrict__ wdownb,
    float* __restrict__ gate_out, int* __restrict__ winner,
    int* __restrict__ blk_cnt, unsigned short* __restrict__ xbf){
  const int tid = threadIdx.x;
  if (blockIdx.x >= 1024){
    const size_t i = ((size_t)(blockIdx.x - 1024) * 256 + tid) * 8;
    floatx4 v0 = *(const floatx4*)(w_down + i);
    floatx4 v1 = *(const floatx4*)(w_down + i + 4);
    short8 p;
    p[0]=(short)f2bf(v0[0]); p[1]=(short)f2bf(v0[1]); p[2]=(short)f2bf(v0[2]); p[3]=(short)f2bf(v0[3]);
    p[4]=(short)f2bf(v1[0]); p[5]=(short)f2bf(v1[1]); p[6]=(short)f2bf(v1[2]); p[7]=(short)f2bf(v1[3]);
    *(short8*)(wdownb + i) = p;
    return;
  }
  __shared__ float ssig[NT * DM];
  __shared__ int swin[16];
  for (int i = tid; i < NT*DM; i += 256) ssig[i] = sig[i];
  __syncthreads();
  const int wv = tid >> 6, lane = tid & 63;

  floatx4 sg[4][4];
  #pragma unroll
  for (int j = 0; j < 4; ++j){
    const int c = j*256 + lane*4;
    #pragma unroll
    for (int tt = 0; tt < 4; ++tt)
      sg[j][tt] = *(const floatx4*)(ssig + tt*DM + c);
  }

  #pragma unroll
  for (int t = 0; t < 4; ++t){
    const int n = blockIdx.x * 16 + wv * 4 + t;
    const float* xr = x + (size_t)n * DM;
    unsigned short* xb = xbf + (size_t)n * 2048 + 1024;
    double a0=0.0, a1=0.0, a2=0.0, a3=0.0;
    #pragma unroll
    for (int j = 0; j < 4; ++j){
      const int c = j*256 + lane*4;
      floatx4 v = *(const floatx4*)(xr + c);
      short4v p;
      p[0]=(short)f2bf(v[0]); p[1]=(short)f2bf(v[1]);
      p[2]=(short)f2bf(v[2]); p[3]=(short)f2bf(v[3]);
      *(short4v*)(xb + c) = p;
      #pragma unroll
      for (int u = 0; u < 4; ++u){
        double xv = (double)v[u];
        a0 += xv * (double)sg[j][0][u];
        a1 += xv * (double)sg[j][1][u];
        a2 += xv * (double)sg[j][2][u];
        a3 += xv * (double)sg[j][3][u];
      }
    }
    #pragma unroll
    for (int off = 32; off > 0; off >>= 1){
      a0 += __shfl_down(a0, off, 64);
      a1 += __shfl_down(a1, off, 64);
      a2 += __shfl_down(a2, off, 64);
      a3 += __shfl_down(a3, off, 64);
    }
    if (lane == 0){
      double s[4] = {a0, a1, a2, a3};
      int w = 0;
      #pragma unroll
      for (int tt = 1; tt < 4; ++tt) if (s[tt] > s[w]) w = tt;   // first-max tiebreak
      floatx4 g = { w==0 ? 1.f:0.f, w==1 ? 1.f:0.f, w==2 ? 1.f:0.f, w==3 ? 1.f:0.f };
      *(floatx4*)(gate_out + (size_t)n * 4) = g;
      winner[n] = w;
      swin[wv*4 + t] = w;
    }
  }
  __syncthreads();
  // fused histogram: this block's 16 winners -> segment blockIdx>>4 counts
  if (tid < NT){
    int c = 0;
    #pragma unroll
    for (int i = 0; i < 16; ++i) c += (swin[i] == tid) ? 1 : 0;
    if (c) atomicAdd(&blk_cnt[(blockIdx.x >> 4) * NT + tid], c);
  }
}

// ---------------- scan / scatter (atomic-free, deterministic) ----------------
__global__ void k_scan(const int* __restrict__ blk_cnt,
                       int* __restrict__ meta, int* __restrict__ blk_base){
  __shared__ int s[256];
  const int tid = threadIdx.x;
  s[tid] = blk_cnt[tid];                    // one coalesced load
  __syncthreads();
  if (tid == 0){
    int tot[NT] = {0,0,0,0};
    for (int b = 0; b < 64; ++b)
      for (int t = 0; t < NT; ++t) tot[t] += s[b*NT + t];
    int off = 0, base[NT];
    for (int t = 0; t < NT; ++t){ meta[t] = tot[t]; meta[4+t] = off; base[t] = off; off += tot[t]; }
    for (int b = 0; b < 64; ++b)
      for (int t = 0; t < NT; ++t){ int c = s[b*NT + t]; s[b*NT + t] = base[t]; base[t] += c; }
  }
  __syncthreads();
  blk_base[tid] = s[tid];                   // parallel store
}

__global__ void k_scatter(const int* __restrict__ winner,
                          const int* __restrict__ blk_base,
                          int* __restrict__ idx){
  __shared__ int wcnt[4][NT];
  const int tid = threadIdx.x, wv = tid >> 6, lane = tid & 63;
  const int n = blockIdx.x * 256 + tid;
  const int w = winner[n];
  unsigned long long mymask = 0;
  #pragma unroll
  for (int t = 0; t < NT; ++t){
    unsigned long long m = __ballot(w == t);
    if (lane == 0) wcnt[wv][t] = __popcll(m);
    if (t == w) mymask = m;
  }
  __syncthreads();
  const unsigned long long below = (lane == 0) ? 0ull : (~0ull >> (64 - lane));
  int pos = blk_base[blockIdx.x * NT + w] + __popcll(mymask & below);
  for (int v = 0; v < wv; ++v) pos += wcnt[v][w];
  idx[pos] = n;
}

// ---------------- GEMM1: hid = relu(xbf[rows] @ wupb[tile]^T + b_up) --------
// R10 structure + R13 T2 LDS XOR-swizzle. Analysis: SQ_LDS_BANK_CONFLICT
// 4.39M/dispatch = ~8 extra cyc per ds_read_b128 — quarter-wave (fixed quad)
// lanes hit only banks {16*(row&1)+4*quad..+3}: 8-way. Fix per rule 21
// (gll16 dest is linear -> swizzle global SOURCE + READ index, same
// involution): stage k-slot' = (lane&3) ^ ((rsub>>1)&3); read slot =
// quad ^ ((l16>>1)&3). All staged row bases are multiples of 16 so
// (row>>1)&3 reduces uniformly. Post-swizzle: 2 lanes/bank-group = free
// (m136). Same data, same MFMA order -> bit-identical output.
__global__ __launch_bounds__(256, 2) void k_gemm1(
    const unsigned short* __restrict__ xbf,   // (ushort*)d_out; row n at n*2048+1024
    const unsigned short* __restrict__ wupb,  // [4096][1024] bf16
    const float* __restrict__ b_up, const int* __restrict__ meta,
    const int* __restrict__ idx, unsigned short* __restrict__ hid){
  // XCD swizzle: r=lin&7 -> (tile, chunk parity); q=lin>>3 -> (nb, chunk half)
  const int lin  = blockIdx.x;                 // [0,4096)
  const int r    = lin & 7, q = lin >> 3;
  const int tile = r >> 1;
  const int nb   = q & 7;
  const int chunk = ((q >> 3) << 1) | (r & 1); // [0,128)
  const int p0   = chunk * 128;

  const int cnt  = meta[tile];
  if (p0 >= cnt) return;
  const int off  = meta[4 + tile];

  __shared__ unsigned short smem[16384];  // 32768B exactly: As0|As1|Bs0|Bs1; prologue nrow + epi overlay
  unsigned short* As0 = smem;
  unsigned short* As1 = smem + 4096;
  unsigned short* Bs0 = smem + 8192;
  unsigned short* Bs1 = smem + 12288;

  const int tid = threadIdx.x;
  const int wv = tid >> 6, lane = tid & 63;
  const int wm = (wv >> 1) * 64, wn = (wv & 1) * 64;
  const int l16 = lane & 15, quad = lane >> 4;
  const int rsub = lane >> 2;          // 0..15
  // T2 swizzled k-slot for staging (global source pre-swizzle, rule 21)
  const int kusw = (((lane & 3) ^ ((lane >> 3) & 3)) * 8);
  // T2 swizzled slot for LDS reads (same involution)
  const int sq8  = (quad ^ ((l16 >> 1) & 3)) * 8;

  // ---- prologue: nrow via smem, consumed into registers, then smem is freed
  int* nrs = (int*)smem;               // first 512B, transient
  if (tid < 128){
    int p = p0 + tid;
    nrs[tid] = idx[off + (p < cnt ? p : cnt - 1)];
  }
  __syncthreads();
  const int ra = wv*32 + rsub;
  const unsigned short* aptr0 = xbf + (size_t)nrs[ra]      * 2048 + 1024 + kusw;
  const unsigned short* aptr1 = xbf + (size_t)nrs[ra + 16] * 2048 + 1024 + kusw;
  int  enr[2][4];                      // epilogue token rows (static-indexed)
  bool ev [2][4];                      // epilogue valid bits
  #pragma unroll
  for (int half = 0; half < 2; ++half){
    #pragma unroll
    for (int s = 0; s < 4; ++s){
      const int lrow = (tid + s*256) >> 4;      // 0..63
      const int m = half*64 + lrow;
      ev [half][s] = (p0 + m < cnt);
      enr[half][s] = nrs[m];
    }
  }
  __syncthreads();                     // all nrs reads done before K-loop overwrites

  const unsigned short* bptr0 = wupb + (size_t)(tile*TU + nb*128 + wv*32 + rsub) * DM + kusw;
  const unsigned short* bptr1 = bptr0 + 16 * DM;

  // wave-uniform LDS dests ([row][32] layout, 64B row stride)
  unsigned short* a0d0 = As0 + (wv*32) * 32;  unsigned short* a0d1 = a0d0 + 16*32;
  unsigned short* a1d0 = As1 + (wv*32) * 32;  unsigned short* a1d1 = a1d0 + 16*32;
  unsigned short* b0d0 = Bs0 + (wv*32) * 32;  unsigned short* b0d1 = b0d0 + 16*32;
  unsigned short* b1d0 = Bs1 + (wv*32) * 32;  unsigned short* b1d1 = b1d0 + 16*32;

  floatx4 acc[4][4];
  #pragma unroll
  for (int i = 0; i < 4; ++i)
    #pragma unroll
    for (int j = 0; j < 4; ++j) acc[i][j] = (floatx4){0.f,0.f,0.f,0.f};

  for (int k0 = 0; k0 < DM; k0 += 64){
    gll16(aptr0 + k0,      a0d0);
    gll16(aptr1 + k0,      a0d1);
    gll16(aptr0 + k0 + 32, a1d0);
    gll16(aptr1 + k0 + 32, a1d1);
    gll16(bptr0 + k0,      b0d0);
    gll16(bptr1 + k0,      b0d1);
    gll16(bptr0 + k0 + 32, b1d0);
    gll16(bptr1 + k0 + 32, b1d1);
    __syncthreads();
    {
      short8 af[4], bfr[4];
      #pragma unroll
      for (int i = 0; i < 4; ++i) af[i]  = *(const short8*)(As0 + (wm + i*16 + l16)*32 + sq8);
      #pragma unroll
      for (int j = 0; j < 4; ++j) bfr[j] = *(const short8*)(Bs0 + (wn + j*16 + l16)*32 + sq8);
      #pragma unroll
      for (int i = 0; i < 4; ++i)
        #pragma unroll
        for (int j = 0; j < 4; ++j)
          acc[i][j] = __builtin_amdgcn_mfma_f32_16x16x32_bf16(af[i], bfr[j], acc[i][j], 0, 0, 0);
    }
    {
      short8 af[4], bfr[4];
      #pragma unroll
      for (int i = 0; i < 4; ++i) af[i]  = *(const short8*)(As1 + (wm + i*16 + l16)*32 + sq8);
      #pragma unroll
      for (int j = 0; j < 4; ++j) bfr[j] = *(const short8*)(Bs1 + (wn + j*16 + l16)*32 + sq8);
      #pragma unroll
      for (int i = 0; i < 4; ++i)
        #pragma unroll
        for (int j = 0; j < 4; ++j)
          acc[i][j] = __builtin_amdgcn_mfma_f32_16x16x32_bf16(af[i], bfr[j], acc[i][j], 0, 0, 0);
    }
    __syncthreads();
  }

  // epilogue: two half-passes of 64 rows through LDS (pad stride 136), wide stores
  const int gcol0 = nb*128;
  #pragma unroll
  for (int half = 0; half < 2; ++half){
    if ((wv >> 1) == half){
      #pragma unroll
      for (int i = 0; i < 4; ++i){
        #pragma unroll
        for (int j = 0; j < 4; ++j){
          const int col = wn + j*16 + l16;          // 0..127
          const float bias = b_up[tile*TU + gcol0 + col];
          #pragma unroll
          for (int r2 = 0; r2 < 4; ++r2){
            const int lrow = i*16 + quad*4 + r2;    // 0..63
            float v = acc[i][j][r2] + bias;
            smem[lrow*136 + col] = f2bf(v > 0.f ? v : 0.f);
          }
        }
      }
    }
    __syncthreads();
    // 64 rows x 16 chunks of 8 ushorts (128 cols); row ids from registers
    #pragma unroll
    for (int s = 0; s < 4; ++s){
      const int c = tid + s*256;
      const int lrow = c >> 4, k8 = (c & 15) * 8;
      if (ev[half][s]){
        short8 vv = *(const short8*)(smem + lrow*136 + k8);
        *(short8*)(hid + (size_t)enr[half][s]*2048 + gcol0 + k8) = vv;
      }
    }
    __syncthreads();
  }
}

// ---------------- GEMM2: out = hid @ wdownb[tile]^T + b_down + zero-fill ----
// BM=32 BN=256, BK=64 paired buffers (R10 structure) + R13 T2 swizzle (same
// involution as gemm1: stage kslot' = (lane&3)^((rsub>>1)&3), read slot =
// quad^((l16>>1)&3); all staged row bases multiples of 16). Tile-into-
// residue XCD swizzle kept. Zero-fill fused after K-loop's final barrier.
__global__ __launch_bounds__(256, 2) void k_gemm2(
    const unsigned short* __restrict__ hid,    // (ushort*)d_out; row n at n*2048
    const unsigned short* __restrict__ wdownb, // [1024][4096] bf16
    const float* __restrict__ b_down, const int* __restrict__ meta,
    const int* __restrict__ idx, float* __restrict__ out){
  const int lin  = blockIdx.x;                 // [0,2048)
  const int r    = lin & 7, q = lin >> 3;
  const int tile = r >> 1;
  const int xx   = (q << 1) | (r & 1);         // [0,512)
  const int p0   = xx * 32;

  const int cnt  = meta[tile];
  if (p0 >= cnt) return;
  const int off  = meta[4 + tile];

  __shared__ unsigned short smem[18432];  // As0|As1 (1024 each) | Bs0|Bs1 (8192 each)
  unsigned short* As0 = smem;
  unsigned short* As1 = smem + 1024;
  unsigned short* Bs0 = smem + 2048;
  unsigned short* Bs1 = smem + 10240;
  float* epi = (float*)smem;              // overlay: 16 rows x 260 floats = 16640B
  __shared__ int nrow[32];

  const int tid = threadIdx.x;
  if (tid < 32){
    int p = p0 + tid;
    nrow[tid] = idx[off + (p < cnt ? p : cnt - 1)];
  }
  __syncthreads();

  const int wv = tid >> 6, lane = tid & 63;
  const int wn = wv * 64;
  const int l16 = lane & 15, quad = lane >> 4;
  const int rsub = lane >> 2;
  const int kusw = (((lane & 3) ^ ((lane >> 3) & 3)) * 8);   // T2 staging swizzle
  const int sq8  = (quad ^ ((l16 >> 1) & 3)) * 8;            // T2 read swizzle

  const int arow = (wv & 1)*16 + rsub;
  const unsigned short* aptr = hid + (size_t)nrow[arow] * 2048 + kusw;
  const int aoff = (wv >> 1) * 32;                     // k-chunk offset
  unsigned short* asd = (wv < 2 ? As0 : As1) + ((wv & 1)*16) * 32;
  const unsigned short* bptr = wdownb + (size_t)(tile*TD + wv*64 + rsub) * DFF + tile*TU + kusw;
  unsigned short* bsd0 = Bs0 + (wv*64) * 32;
  unsigned short* bsd1 = Bs1 + (wv*64) * 32;

  floatx4 acc[2][4];
  #pragma unroll
  for (int i = 0; i < 2; ++i)
    #pragma unroll
    for (int j = 0; j < 4; ++j) acc[i][j] = (floatx4){0.f,0.f,0.f,0.f};

  for (int k0 = 0; k0 < TU; k0 += 64){
    gll16(aptr + k0 + aoff, asd);
    gll16(bptr + k0,               bsd0);
    gll16(bptr + k0 + 16*DFF,      bsd0 + 16*32);
    gll16(bptr + k0 + 32*DFF,      bsd0 + 32*32);
    gll16(bptr + k0 + 48*DFF,      bsd0 + 48*32);
    gll16(bptr + k0 + 32,          bsd1);
    gll16(bptr + k0 + 32 + 16*DFF, bsd1 + 16*32);
    gll16(bptr + k0 + 32 + 32*DFF, bsd1 + 32*32);
    gll16(bptr + k0 + 32 + 48*DFF, bsd1 + 48*32);
    __syncthreads();
    {
      short8 af[2], bfr[4];
      #pragma unroll
      for (int i = 0; i < 2; ++i) af[i]  = *(const short8*)(As0 + (i*16 + l16)*32 + sq8);
      #pragma unroll
      for (int j = 0; j < 4; ++j) bfr[j] = *(const short8*)(Bs0 + (wn + j*16 + l16)*32 + sq8);
      #pragma unroll
      for (int i = 0; i < 2; ++i)
        #pragma unroll
        for (int j = 0; j < 4; ++j)
          acc[i][j] = __builtin_amdgcn_mfma_f32_16x16x32_bf16(af[i], bfr[j], acc[i][j], 0, 0, 0);
    }
    {
      short8 af[2], bfr[4];
      #pragma unroll
      for (int i = 0; i < 2; ++i) af[i]  = *(const short8*)(As1 + (i*16 + l16)*32 + sq8);
      #pragma unroll
      for (int j = 0; j < 4; ++j) bfr[j] = *(const short8*)(Bs1 + (wn + j*16 + l16)*32 + sq8);
      #pragma unroll
      for (int i = 0; i < 2; ++i)
        #pragma unroll
        for (int j = 0; j < 4; ++j)
          acc[i][j] = __builtin_amdgcn_mfma_f32_16x16x32_bf16(af[i], bfr[j], acc[i][j], 0, 0, 0);
    }
    __syncthreads();
  }

  // zero-fill non-winner 256-col blocks of OWN tokens (hid reads all drained)
  const floatx4 z4 = {0.f, 0.f, 0.f, 0.f};
  #pragma unroll
  for (int cb = 0; cb < 4; ++cb){
    if (cb == tile) continue;
    for (int c = tid; c < 32*64; c += 256){
      const int rowl = c >> 6, c4 = (c & 63) * 4;
      if (p0 + rowl < cnt)
        *(floatx4*)(out + (size_t)nrow[rowl]*DM + cb*256 + c4) = z4;
    }
  }

  // epilogue: two half-passes of 16 rows via LDS fp32 (pad stride 260), float4 stores
  #pragma unroll
  for (int half = 0; half < 2; ++half){
    #pragma unroll
    for (int j = 0; j < 4; ++j){
      const int col = wn + j*16 + l16;              // 0..255
      const float bias = b_down[tile*TD + col];
      #pragma unroll
      for (int r2 = 0; r2 < 4; ++r2){
        const int lrow = quad*4 + r2;               // 0..15
        epi[lrow*260 + col] = acc[half][j][r2] + bias;
      }
    }
    __syncthreads();
    #pragma unroll
    for (int c = tid; c < 1024; c += 256){          // 16 rows x 64 float4 chunks
      const int lrow = c >> 6, c4 = (c & 63) * 4;
      const int m = half*16 + lrow;
      if (p0 + m < cnt){
        floatx4 v = *(const floatx4*)(epi + lrow*260 + c4);
        *(floatx4*)(out + (size_t)nrow[m]*DM + tile*TD + c4) = v;
      }
    }
    __syncthreads();
  }
}

extern "C" void kernel_launch(void* const* d_in, const int* in_sizes, int n_in,
                              void* d_out, int out_size, void* d_ws, size_t ws_size,
                              hipStream_t stream){
  const float* x      = (const float*)d_in[0];
  const float* w_up   = (const float*)d_in[1];
  const float* b_up   = (const float*)d_in[2];
  const float* w_down = (const float*)d_in[3];
  const float* b_down = (const float*)d_in[4];

  // ws layout (~17.3 MB; proven layout)
  unsigned short* wupb   = (unsigned short*)d_ws;            // 4096*1024 bf16 = 8 MB
  unsigned short* wdownb = wupb + (size_t)DFF * DM;          // 1024*4096 bf16 = 8 MB
  float* partial = (float*)(wdownb + (size_t)DM * DFF);      // 262144 floats = 1 MB
  float* sig     = partial + 262144;                         // 4096 floats
  int*   ints    = (int*)(sig + 4096);
  int*   winner   = ints;                                    // 16384
  int*   idx      = ints + 16384;                            // 16384
  int*   meta     = ints + 32768;                            // [0..3]=counts [4..7]=offsets
  int*   blk_cnt  = ints + 32776;                            // [64][4]
  int*   blk_base = ints + 33032;                            // [64][4]

  float*          out  = (float*)d_out;
  float*          gate = out + (size_t)N_TOK * DM;
  unsigned short* ob16 = (unsigned short*)d_out;  // row n: hid at n*2048, xbf at n*2048+1024

  k_prep      <<<dim3(256),  256, 0, stream>>>(w_up, partial, wupb);
  k_sig_final <<<dim3(16),   256, 0, stream>>>(partial, sig, blk_cnt);
  k_route     <<<dim3(3072), 256, 0, stream>>>(x, sig, w_down, wdownb, gate, winner, blk_cnt, ob16);
  k_scan      <<<dim3(1),    256, 0, stream>>>(blk_cnt, meta, blk_base);
  k_scatter   <<<dim3(64),   256, 0, stream>>>(winner, blk_base, idx);
  k_gemm1     <<<dim3(4096), 256, 0, stream>>>(ob16, wupb, b_up, meta, idx, ob16);
  k_gemm2     <<<dim3(2048), 256, 0, stream>>>(ob16, wdownb, b_down, meta, idx, out);
}

// Round 14
// 243.029 us; speedup vs baseline: 1.0699x; 1.0446x over previous
//
#include <hip/hip_runtime.h>
#include <stdint.h>
#include <stddef.h>

#define N_TOK 16384
#define DM    1024
#define DFF   4096
#define NT    4
#define TU    1024   // d_ff tile
#define TD    256    // d_model tile

typedef __attribute__((ext_vector_type(8))) short  short8;
typedef __attribute__((ext_vector_type(4))) short  short4v;
typedef __attribute__((ext_vector_type(4))) float  floatx4;

__device__ inline unsigned short f2bf(float f){
  union { float f; uint32_t u; } v; v.f = f;
  uint32_t u = v.u + 0x7FFFu + ((v.u >> 16) & 1u);   // RNE
  return (unsigned short)(u >> 16);
}

// async global->LDS, 16B per lane; lds dest is wave-uniform, lane i lands at +16*i
__device__ __forceinline__ void gll16(const void* g, void* l){
  __builtin_amdgcn_global_load_lds(
      (const __attribute__((address_space(1))) unsigned int*)g,
      (__attribute__((address_space(3))) unsigned int*)l,
      16, 0, 0);
}

// ---------------- prep: sig partial sums + w_up->bf16 ----------------------
__global__ void k_prep(const float* __restrict__ w_up,
                       float* __restrict__ partial,
                       unsigned short* __restrict__ wupb){
  const int tid = threadIdx.x;
  const int b = blockIdx.x;
  const int tile = b >> 6, chunk = b & 63;
  const int c0 = tid * 4;
  const int row0 = tile*TU + chunk*16;
  float s0=0.f, s1=0.f, s2=0.f, s3=0.f;
  const float* base = w_up + (size_t)row0 * DM + c0;
  #pragma unroll
  for (int r = 0; r < 16; ++r){
    floatx4 v = *(const floatx4*)(base + (size_t)r * DM);
    s0 += v[0]; s1 += v[1]; s2 += v[2]; s3 += v[3];
    short4v p;
    p[0]=(short)f2bf(v[0]); p[1]=(short)f2bf(v[1]);
    p[2]=(short)f2bf(v[2]); p[3]=(short)f2bf(v[3]);
    *(short4v*)(wupb + (size_t)(row0 + r) * DM + c0) = p;
  }
  float* p = partial + ((size_t)tile*DM + c0) * 64 + chunk;
  p[0] = s0; p[64] = s1; p[128] = s2; p[192] = s3;
}

// ---------------- sig finalize (+ zero blk_cnt for route's fused hist) ------
__global__ void k_sig_final(const float* __restrict__ partial,
                            float* __restrict__ sig,
                            int* __restrict__ blk_cnt){
  if (blockIdx.x == 0) blk_cnt[threadIdx.x] = 0;   // 256 ints, re-zeroed each replay
  const int g = blockIdx.x * 256 + threadIdx.x;    // 0..4095 = tile*1024+col
  const float* p = partial + (size_t)g * 64;
  float s = 0.f;
  #pragma unroll
  for (int i = 0; i < 64; ++i) s += p[i];
  sig[g] = (s > 0.f) ? 1.f : ((s < 0.f) ? -1.f : 0.f);
}

// ---------------- routing (+ fused w_down conv + fused histogram) -----------
// blocks [0,1024) = routing (16 tokens/block, 4/wave); blocks [1024,3072) =
// w_down bf16 conversion (m114 overlap). fp64 sum order UNCHANGED -> winner
// bit-identical. Per-block winner counts atomicAdd'ed into blk_cnt
// (integer add commutative -> deterministic; scan/scatter inputs identical).
// xbf row n lives in SECOND 2048B of out row n (ushort offset n*2048+1024).
__global__ __launch_bounds__(256) void k_route(
    const float* __restrict__ x, const float* __restrict__ sig,
    const float* __restrict__ w_down, unsigned short* __restrict__ wdownb,
    float* __restrict__ gate_out, int* __restrict__ winner,
    int* __restrict__ blk_cnt, unsigned short* __restrict__ xbf){
  const int tid = threadIdx.x;
  if (blockIdx.x >= 1024){
    const size_t i = ((size_t)(blockIdx.x - 1024) * 256 + tid) * 8;
    floatx4 v0 = *(const floatx4*)(w_down + i);
    floatx4 v1 = *(const floatx4*)(w_down + i + 4);
    short8 p;
    p[0]=(short)f2bf(v0[0]); p[1]=(short)f2bf(v0[1]); p[2]=(short)f2bf(v0[2]); p[3]=(short)f2bf(v0[3]);
    p[4]=(short)f2bf(v1[0]); p[5]=(short)f2bf(v1[1]); p[6]=(short)f2bf(v1[2]); p[7]=(short)f2bf(v1[3]);
    *(short8*)(wdownb + i) = p;
    return;
  }
  __shared__ float ssig[NT * DM];
  __shared__ int swin[16];
  for (int i = tid; i < NT*DM; i += 256) ssig[i] = sig[i];
  __syncthreads();
  const int wv = tid >> 6, lane = tid & 63;

  floatx4 sg[4][4];
  #pragma unroll
  for (int j = 0; j < 4; ++j){
    const int c = j*256 + lane*4;
    #pragma unroll
    for (int tt = 0; tt < 4; ++tt)
      sg[j][tt] = *(const floatx4*)(ssig + tt*DM + c);
  }

  #pragma unroll
  for (int t = 0; t < 4; ++t){
    const int n = blockIdx.x * 16 + wv * 4 + t;
    const float* xr = x + (size_t)n * DM;
    unsigned short* xb = xbf + (size_t)n * 2048 + 1024;
    double a0=0.0, a1=0.0, a2=0.0, a3=0.0;
    #pragma unroll
    for (int j = 0; j < 4; ++j){
      const int c = j*256 + lane*4;
      floatx4 v = *(const floatx4*)(xr + c);
      short4v p;
      p[0]=(short)f2bf(v[0]); p[1]=(short)f2bf(v[1]);
      p[2]=(short)f2bf(v[2]); p[3]=(short)f2bf(v[3]);
      *(short4v*)(xb + c) = p;
      #pragma unroll
      for (int u = 0; u < 4; ++u){
        double xv = (double)v[u];
        a0 += xv * (double)sg[j][0][u];
        a1 += xv * (double)sg[j][1][u];
        a2 += xv * (double)sg[j][2][u];
        a3 += xv * (double)sg[j][3][u];
      }
    }
    #pragma unroll
    for (int off = 32; off > 0; off >>= 1){
      a0 += __shfl_down(a0, off, 64);
      a1 += __shfl_down(a1, off, 64);
      a2 += __shfl_down(a2, off, 64);
      a3 += __shfl_down(a3, off, 64);
    }
    if (lane == 0){
      double s[4] = {a0, a1, a2, a3};
      int w = 0;
      #pragma unroll
      for (int tt = 1; tt < 4; ++tt) if (s[tt] > s[w]) w = tt;   // first-max tiebreak
      floatx4 g = { w==0 ? 1.f:0.f, w==1 ? 1.f:0.f, w==2 ? 1.f:0.f, w==3 ? 1.f:0.f };
      *(floatx4*)(gate_out + (size_t)n * 4) = g;
      winner[n] = w;
      swin[wv*4 + t] = w;
    }
  }
  __syncthreads();
  // fused histogram: this block's 16 winners -> segment blockIdx>>4 counts
  if (tid < NT){
    int c = 0;
    #pragma unroll
    for (int i = 0; i < 16; ++i) c += (swin[i] == tid) ? 1 : 0;
    if (c) atomicAdd(&blk_cnt[(blockIdx.x >> 4) * NT + tid], c);
  }
}

// ---------------- scan / scatter (atomic-free, deterministic) ----------------
__global__ void k_scan(const int* __restrict__ blk_cnt,
                       int* __restrict__ meta, int* __restrict__ blk_base){
  __shared__ int s[256];
  const int tid = threadIdx.x;
  s[tid] = blk_cnt[tid];                    // one coalesced load
  __syncthreads();
  if (tid == 0){
    int tot[NT] = {0,0,0,0};
    for (int b = 0; b < 64; ++b)
      for (int t = 0; t < NT; ++t) tot[t] += s[b*NT + t];
    int off = 0, base[NT];
    for (int t = 0; t < NT; ++t){ meta[t] = tot[t]; meta[4+t] = off; base[t] = off; off += tot[t]; }
    for (int b = 0; b < 64; ++b)
      for (int t = 0; t < NT; ++t){ int c = s[b*NT + t]; s[b*NT + t] = base[t]; base[t] += c; }
  }
  __syncthreads();
  blk_base[tid] = s[tid];                   // parallel store
}

__global__ void k_scatter(const int* __restrict__ winner,
                          const int* __restrict__ blk_base,
                          int* __restrict__ idx){
  __shared__ int wcnt[4][NT];
  const int tid = threadIdx.x, wv = tid >> 6, lane = tid & 63;
  const int n = blockIdx.x * 256 + tid;
  const int w = winner[n];
  unsigned long long mymask = 0;
  #pragma unroll
  for (int t = 0; t < NT; ++t){
    unsigned long long m = __ballot(w == t);
    if (lane == 0) wcnt[wv][t] = __popcll(m);
    if (t == w) mymask = m;
  }
  __syncthreads();
  const unsigned long long below = (lane == 0) ? 0ull : (~0ull >> (64 - lane));
  int pos = blk_base[blockIdx.x * NT + w] + __popcll(mymask & below);
  for (int v = 0; v < wv; ++v) pos += wcnt[v][w];
  idx[pos] = n;
}

// ---------------- GEMM1: hid = relu(xbf[rows] @ wupb[tile]^T + b_up) --------
// R13 version VERBATIM (50us, MfmaUtil 26, conflicts 131K — sentinel).
__global__ __launch_bounds__(256, 2) void k_gemm1(
    const unsigned short* __restrict__ xbf,   // (ushort*)d_out; row n at n*2048+1024
    const unsigned short* __restrict__ wupb,  // [4096][1024] bf16
    const float* __restrict__ b_up, const int* __restrict__ meta,
    const int* __restrict__ idx, unsigned short* __restrict__ hid){
  // XCD swizzle: r=lin&7 -> (tile, chunk parity); q=lin>>3 -> (nb, chunk half)
  const int lin  = blockIdx.x;                 // [0,4096)
  const int r    = lin & 7, q = lin >> 3;
  const int tile = r >> 1;
  const int nb   = q & 7;
  const int chunk = ((q >> 3) << 1) | (r & 1); // [0,128)
  const int p0   = chunk * 128;

  const int cnt  = meta[tile];
  if (p0 >= cnt) return;
  const int off  = meta[4 + tile];

  __shared__ unsigned short smem[16384];  // 32768B exactly: As0|As1|Bs0|Bs1; prologue nrow + epi overlay
  unsigned short* As0 = smem;
  unsigned short* As1 = smem + 4096;
  unsigned short* Bs0 = smem + 8192;
  unsigned short* Bs1 = smem + 12288;

  const int tid = threadIdx.x;
  const int wv = tid >> 6, lane = tid & 63;
  const int wm = (wv >> 1) * 64, wn = (wv & 1) * 64;
  const int l16 = lane & 15, quad = lane >> 4;
  const int rsub = lane >> 2;          // 0..15
  // T2 swizzled k-slot for staging (global source pre-swizzle, rule 21)
  const int kusw = (((lane & 3) ^ ((lane >> 3) & 3)) * 8);
  // T2 swizzled slot for LDS reads (same involution)
  const int sq8  = (quad ^ ((l16 >> 1) & 3)) * 8;

  // ---- prologue: nrow via smem, consumed into registers, then smem is freed
  int* nrs = (int*)smem;               // first 512B, transient
  if (tid < 128){
    int p = p0 + tid;
    nrs[tid] = idx[off + (p < cnt ? p : cnt - 1)];
  }
  __syncthreads();
  const int ra = wv*32 + rsub;
  const unsigned short* aptr0 = xbf + (size_t)nrs[ra]      * 2048 + 1024 + kusw;
  const unsigned short* aptr1 = xbf + (size_t)nrs[ra + 16] * 2048 + 1024 + kusw;
  int  enr[2][4];                      // epilogue token rows (static-indexed)
  bool ev [2][4];                      // epilogue valid bits
  #pragma unroll
  for (int half = 0; half < 2; ++half){
    #pragma unroll
    for (int s = 0; s < 4; ++s){
      const int lrow = (tid + s*256) >> 4;      // 0..63
      const int m = half*64 + lrow;
      ev [half][s] = (p0 + m < cnt);
      enr[half][s] = nrs[m];
    }
  }
  __syncthreads();                     // all nrs reads done before K-loop overwrites

  const unsigned short* bptr0 = wupb + (size_t)(tile*TU + nb*128 + wv*32 + rsub) * DM + kusw;
  const unsigned short* bptr1 = bptr0 + 16 * DM;

  // wave-uniform LDS dests ([row][32] layout, 64B row stride)
  unsigned short* a0d0 = As0 + (wv*32) * 32;  unsigned short* a0d1 = a0d0 + 16*32;
  unsigned short* a1d0 = As1 + (wv*32) * 32;  unsigned short* a1d1 = a1d0 + 16*32;
  unsigned short* b0d0 = Bs0 + (wv*32) * 32;  unsigned short* b0d1 = b0d0 + 16*32;
  unsigned short* b1d0 = Bs1 + (wv*32) * 32;  unsigned short* b1d1 = b1d0 + 16*32;

  floatx4 acc[4][4];
  #pragma unroll
  for (int i = 0; i < 4; ++i)
    #pragma unroll
    for (int j = 0; j < 4; ++j) acc[i][j] = (floatx4){0.f,0.f,0.f,0.f};

  for (int k0 = 0; k0 < DM; k0 += 64){
    gll16(aptr0 + k0,      a0d0);
    gll16(aptr1 + k0,      a0d1);
    gll16(aptr0 + k0 + 32, a1d0);
    gll16(aptr1 + k0 + 32, a1d1);
    gll16(bptr0 + k0,      b0d0);
    gll16(bptr1 + k0,      b0d1);
    gll16(bptr0 + k0 + 32, b1d0);
    gll16(bptr1 + k0 + 32, b1d1);
    __syncthreads();
    {
      short8 af[4], bfr[4];
      #pragma unroll
      for (int i = 0; i < 4; ++i) af[i]  = *(const short8*)(As0 + (wm + i*16 + l16)*32 + sq8);
      #pragma unroll
      for (int j = 0; j < 4; ++j) bfr[j] = *(const short8*)(Bs0 + (wn + j*16 + l16)*32 + sq8);
      #pragma unroll
      for (int i = 0; i < 4; ++i)
        #pragma unroll
        for (int j = 0; j < 4; ++j)
          acc[i][j] = __builtin_amdgcn_mfma_f32_16x16x32_bf16(af[i], bfr[j], acc[i][j], 0, 0, 0);
    }
    {
      short8 af[4], bfr[4];
      #pragma unroll
      for (int i = 0; i < 4; ++i) af[i]  = *(const short8*)(As1 + (wm + i*16 + l16)*32 + sq8);
      #pragma unroll
      for (int j = 0; j < 4; ++j) bfr[j] = *(const short8*)(Bs1 + (wn + j*16 + l16)*32 + sq8);
      #pragma unroll
      for (int i = 0; i < 4; ++i)
        #pragma unroll
        for (int j = 0; j < 4; ++j)
          acc[i][j] = __builtin_amdgcn_mfma_f32_16x16x32_bf16(af[i], bfr[j], acc[i][j], 0, 0, 0);
    }
    __syncthreads();
  }

  // epilogue: two half-passes of 64 rows through LDS (pad stride 136), wide stores
  const int gcol0 = nb*128;
  #pragma unroll
  for (int half = 0; half < 2; ++half){
    if ((wv >> 1) == half){
      #pragma unroll
      for (int i = 0; i < 4; ++i){
        #pragma unroll
        for (int j = 0; j < 4; ++j){
          const int col = wn + j*16 + l16;          // 0..127
          const float bias = b_up[tile*TU + gcol0 + col];
          #pragma unroll
          for (int r2 = 0; r2 < 4; ++r2){
            const int lrow = i*16 + quad*4 + r2;    // 0..63
            float v = acc[i][j][r2] + bias;
            smem[lrow*136 + col] = f2bf(v > 0.f ? v : 0.f);
          }
        }
      }
    }
    __syncthreads();
    // 64 rows x 16 chunks of 8 ushorts (128 cols); row ids from registers
    #pragma unroll
    for (int s = 0; s < 4; ++s){
      const int c = tid + s*256;
      const int lrow = c >> 4, k8 = (c & 15) * 8;
      if (ev[half][s]){
        short8 vv = *(const short8*)(smem + lrow*136 + k8);
        *(short8*)(hid + (size_t)enr[half][s]*2048 + gcol0 + k8) = vv;
      }
    }
    __syncthreads();
  }
}

// ---------------- GEMM2: out = hid @ wdownb[tile]^T + b_down + zero-fill ----
// R14: BM=64 x BN=128 (was 32x256). Traffic audit: at BM=32 each tile's
// 512KB B panel was read by cnt/32 blocks = 256MB B + 32MB hid = 288MB,
// L2-BW-bound (~2 XCD-L2s/tile serve it). BM=64/BN=128: B reads halve
// (128MB), hid reads double (64MB, 2nd read same-XCD L2-hot) -> 192MB
// (-33%). Grid stays 2048 decl / ~512 active = 2 blk/CU (R3's BM=64 failure
// was BN=256 -> 1 blk/CU). Same 4-wave 2-barrier structure, 16 MFMA/wave/
// step, T2 swizzle (row bases stay multiples of 16), LDS 24.6KB. Each block
// handles col-panel pnl (128 cols); zero-fill split per panel (disjoint
// halves). MFMA k-order per accumulator unchanged -> bit-identical.
// XCD tile-residency swizzle kept: residue = 2*tile + chunk-parity.
__global__ __launch_bounds__(256, 2) void k_gemm2(
    const unsigned short* __restrict__ hid,    // (ushort*)d_out; row n at n*2048
    const unsigned short* __restrict__ wdownb, // [1024][4096] bf16
    const float* __restrict__ b_down, const int* __restrict__ meta,
    const int* __restrict__ idx, float* __restrict__ out){
  const int lin  = blockIdx.x;                 // [0,2048)
  const int r    = lin & 7, q = lin >> 3;      // q in [0,256)
  const int tile = r >> 1;
  const int pnl  = q & 1;                      // col panel: 0 or 1 (128 cols)
  const int chunk = ((q >> 1) << 1) | (r & 1); // [0,256) token chunk of 64
  const int p0   = chunk * 64;

  const int cnt  = meta[tile];
  if (p0 >= cnt) return;
  const int off  = meta[4 + tile];

  // As0 [0,2048) 64x32 | As1 [2048,4096) | Bs0 [4096,8192) 128x32 | Bs1 [8192,12288)
  __shared__ unsigned short smem[12288];       // 24576B
  float* epi = (float*)smem;                   // overlay: 32 rows x 132 f32 = 16896B
  __shared__ int nrow[64];

  const int tid = threadIdx.x;
  if (tid < 64){
    int p = p0 + tid;
    nrow[tid] = idx[off + (p < cnt ? p : cnt - 1)];
  }
  __syncthreads();

  const int wv = tid >> 6, lane = tid & 63;
  const int wr = wv >> 1, wc = wv & 1;         // wave tile: rows wr*32, cols wc*64
  const int l16 = lane & 15, quad = lane >> 4;
  const int rsub = lane >> 2;
  const int kusw = (((lane & 3) ^ ((lane >> 3) & 3)) * 8);   // T2 staging swizzle
  const int sq8  = (quad ^ ((l16 >> 1) & 3)) * 8;            // T2 read swizzle

  // A: wave wv stages rows wv*16..+15 (both k-chunks)
  const unsigned short* aptr = hid + (size_t)nrow[wv*16 + rsub] * 2048 + kusw;
  unsigned short* const asd0 = smem + (wv*16) * 32;          // As0 section
  unsigned short* const asd1 = asd0 + 2048;                  // As1 section
  // B: wave wv stages panel rows wv*32..+31 per chunk (2 gll16 each)
  const unsigned short* bptr = wdownb + (size_t)(tile*TD + pnl*128 + wv*32 + rsub) * DFF
                                      + tile*TU + kusw;
  unsigned short* const bsd0 = smem + 4096 + (wv*32) * 32;
  unsigned short* const bsd1 = bsd0 + 4096;

  floatx4 acc[2][4];
  #pragma unroll
  for (int i = 0; i < 2; ++i)
    #pragma unroll
    for (int j = 0; j < 4; ++j) acc[i][j] = (floatx4){0.f,0.f,0.f,0.f};

  for (int k0 = 0; k0 < TU; k0 += 64){
    gll16(aptr + k0,               asd0);
    gll16(aptr + k0 + 32,          asd1);
    gll16(bptr + k0,               bsd0);
    gll16(bptr + k0 + 16*DFF,      bsd0 + 512);
    gll16(bptr + k0 + 32,          bsd1);
    gll16(bptr + k0 + 32 + 16*DFF, bsd1 + 512);
    __syncthreads();
    {
      short8 af[2], bfr[4];
      #pragma unroll
      for (int i = 0; i < 2; ++i) af[i]  = *(const short8*)(smem + (wr*32 + i*16 + l16)*32 + sq8);
      #pragma unroll
      for (int j = 0; j < 4; ++j) bfr[j] = *(const short8*)(smem + 4096 + (wc*64 + j*16 + l16)*32 + sq8);
      #pragma unroll
      for (int i = 0; i < 2; ++i)
        #pragma unroll
        for (int j = 0; j < 4; ++j)
          acc[i][j] = __builtin_amdgcn_mfma_f32_16x16x32_bf16(af[i], bfr[j], acc[i][j], 0, 0, 0);
    }
    {
      short8 af[2], bfr[4];
      #pragma unroll
      for (int i = 0; i < 2; ++i) af[i]  = *(const short8*)(smem + 2048 + (wr*32 + i*16 + l16)*32 + sq8);
      #pragma unroll
      for (int j = 0; j < 4; ++j) bfr[j] = *(const short8*)(smem + 8192 + (wc*64 + j*16 + l16)*32 + sq8);
      #pragma unroll
      for (int i = 0; i < 2; ++i)
        #pragma unroll
        for (int j = 0; j < 4; ++j)
          acc[i][j] = __builtin_amdgcn_mfma_f32_16x16x32_bf16(af[i], bfr[j], acc[i][j], 0, 0, 0);
    }
    __syncthreads();
  }

  // zero-fill: non-winner tile blocks, THIS panel's 128-col half only
  // (panels of a chunk cover disjoint halves -> no duplicate writes)
  const floatx4 z4 = {0.f, 0.f, 0.f, 0.f};
  #pragma unroll
  for (int cb = 0; cb < 4; ++cb){
    if (cb == tile) continue;
    for (int c = tid; c < 64*32; c += 256){
      const int rowl = c >> 5, c4 = (c & 31) * 4;
      if (p0 + rowl < cnt)
        *(floatx4*)(out + (size_t)nrow[rowl]*DM + cb*256 + pnl*128 + c4) = z4;
    }
  }

  // epilogue: two half-passes of 32 rows via LDS fp32 (pad stride 132)
  const int gcol0 = tile*TD + pnl*128;
  #pragma unroll
  for (int h = 0; h < 2; ++h){
    if (wr == h){
      #pragma unroll
      for (int i = 0; i < 2; ++i){
        #pragma unroll
        for (int j = 0; j < 4; ++j){
          const int col = wc*64 + j*16 + l16;         // 0..127
          const float bias = b_down[gcol0 + col];
          #pragma unroll
          for (int r2 = 0; r2 < 4; ++r2){
            const int lrow = i*16 + quad*4 + r2;      // 0..31
            epi[lrow*132 + col] = acc[i][j][r2] + bias;
          }
        }
      }
    }
    __syncthreads();
    #pragma unroll
    for (int c = tid; c < 1024; c += 256){            // 32 rows x 32 float4 chunks
      const int lrow = c >> 5, c4 = (c & 31) * 4;
      const int m = h*32 + lrow;
      if (p0 + m < cnt){
        floatx4 v = *(const floatx4*)(epi + lrow*132 + c4);
        *(floatx4*)(out + (size_t)nrow[m]*DM + gcol0 + c4) = v;
      }
    }
    __syncthreads();
  }
}

extern "C" void kernel_launch(void* const* d_in, const int* in_sizes, int n_in,
                              void* d_out, int out_size, void* d_ws, size_t ws_size,
                              hipStream_t stream){
  const float* x      = (const float*)d_in[0];
  const float* w_up   = (const float*)d_in[1];
  const float* b_up   = (const float*)d_in[2];
  const float* w_down = (const float*)d_in[3];
  const float* b_down = (const float*)d_in[4];

  // ws layout (~17.3 MB; proven layout)
  unsigned short* wupb   = (unsigned short*)d_ws;            // 4096*1024 bf16 = 8 MB
  unsigned short* wdownb = wupb + (size_t)DFF * DM;          // 1024*4096 bf16 = 8 MB
  float* partial = (float*)(wdownb + (size_t)DM * DFF);      // 262144 floats = 1 MB
  float* sig     = partial + 262144;                         // 4096 floats
  int*   ints    = (int*)(sig + 4096);
  int*   winner   = ints;                                    // 16384
  int*   idx      = ints + 16384;                            // 16384
  int*   meta     = ints + 32768;                            // [0..3]=counts [4..7]=offsets
  int*   blk_cnt  = ints + 32776;                            // [64][4]
  int*   blk_base = ints + 33032;                            // [64][4]

  float*          out  = (float*)d_out;
  float*          gate = out + (size_t)N_TOK * DM;
  unsigned short* ob16 = (unsigned short*)d_out;  // row n: hid at n*2048, xbf at n*2048+1024

  k_prep      <<<dim3(256),  256, 0, stream>>>(w_up, partial, wupb);
  k_sig_final <<<dim3(16),   256, 0, stream>>>(partial, sig, blk_cnt);
  k_route     <<<dim3(3072), 256, 0, stream>>>(x, sig, w_down, wdownb, gate, winner, blk_cnt, ob16);
  k_scan      <<<dim3(1),    256, 0, stream>>>(blk_cnt, meta, blk_base);
  k_scatter   <<<dim3(64),   256, 0, stream>>>(winner, blk_base, idx);
  k_gemm1     <<<dim3(4096), 256, 0, stream>>>(ob16, wupb, b_up, meta, idx, ob16);
  k_gemm2     <<<dim3(2048), 256, 0, stream>>>(ob16, wdownb, b_down, meta, idx, out);
}